// Round 8
// baseline (271.117 us; speedup 1.0000x reference)
//
#include <hip/hip_runtime.h>
#include <stdint.h>

#define BATCH 64
#define SLEN 512
#define HID 128
#define NHEAD 4
#define DPROJ 512            // HID * NHEAD
#define MTOT (BATCH * SLEN)  // 32768
#define SCALE 0.08838834764831845f
#define LOG2E 1.4426950408889634f

using short8 = __attribute__((ext_vector_type(8))) short;
using f32x4  = __attribute__((ext_vector_type(4))) float;
using u32x4  = __attribute__((ext_vector_type(4))) unsigned int;
using u32x2  = __attribute__((ext_vector_type(2))) unsigned int;
using us4    = __attribute__((ext_vector_type(4))) unsigned short;

__device__ __forceinline__ unsigned short f2bf(float f) {
  unsigned int u = __float_as_uint(f);
  u += 0x7fffu + ((u >> 16) & 1u);   // round-to-nearest-even
  return (unsigned short)(u >> 16);
}

// ---------------------------------------------------------------------------
// Kernel 0: prep — R17 (frozen). Blocks 0..1023: weight cast+transpose.
// Blocks 1024..2047: mask bit-pack, vectorized 16 B/lane + shfl_xor pack.
// ---------------------------------------------------------------------------
__global__ __launch_bounds__(256) void prep_kernel(
    const float* __restrict__ Wq,
    const float* __restrict__ Wk,
    const float* __restrict__ Wv,
    const float* __restrict__ Wo,
    const int* __restrict__ mask,
    unsigned short* __restrict__ WT,
    unsigned short* __restrict__ WoT,
    unsigned int* __restrict__ mbits)
{
  if (blockIdx.x < 1024) {
    int idx = blockIdx.x * 256 + threadIdx.x;
    int z = idx >> 16;
    int i = idx & 65535;
    if (z < 3) {
      const float* W = (z == 0) ? Wq : (z == 1) ? Wk : Wv;
      float scale = (z == 0) ? (SCALE * LOG2E) : 1.0f;  // exp2 form
      int k = i >> 9;
      int n = i & 511;
      WT[(size_t)z * 65536 + (size_t)n * 128 + k] = f2bf(W[i] * scale);
    } else {
      int k = i >> 7;
      int n = i & 127;
      WoT[(size_t)n * 512 + k] = f2bf(Wo[i]);
    }
  } else {
    // mask -> bitmask: 1024 blocks x 4 waves x 16 tiles of 256 ints.
    const int l = threadIdx.x & 63;
    const int wv = threadIdx.x >> 6;
    const int m = blockIdx.x - 1024;
    #pragma unroll 4
    for (int it = 0; it < 16; ++it) {
      size_t tile = (size_t)m * 64 + (size_t)wv * 16 + it;
      u32x4 v = *(const u32x4*)(mask + tile * 256 + l * 4);
      unsigned nib = (v[0] ? 1u : 0u) | (v[1] ? 2u : 0u) |
                     (v[2] ? 4u : 0u) | (v[3] ? 8u : 0u);
      unsigned a  = nib | ((unsigned)__shfl_xor((int)nib, 1, 64) << 4);
      unsigned b2 = a   | ((unsigned)__shfl_xor((int)a,   2, 64) << 8);
      unsigned c  = b2  | ((unsigned)__shfl_xor((int)b2,  4, 64) << 16);
      if ((l & 7) == 0) mbits[tile * 8 + (l >> 3)] = c;
    }
  }
}

// ---------------------------------------------------------------------------
// Kernel 1: QKV projection — R18. R7 measured 60us at 2.8x BW floor,
// occupancy 19% (LDS 71,680 -> 2 blocks/CU = 2 waves/SIMD), latency-bound.
// Fix: A-tile moved from LDS to REGISTERS. A is identical for all 3 z and
// every fragment is per-thread-static -> qa[2][2][4] short8 (64 VGPR),
// loaded+converted once from fp32 enc (bit-identical f2bf). Ald deleted:
// LDS 71,680 -> 36,864; launch_bounds(256,3) pins VGPR<=170 -> 3 waves/SIMD
// = 12 waves/CU (was 8). A ds_reads gone (96 -> 48 b128/thread) and the 3x
// A re-read across z disappears. B pipeline unchanged (dbuf + reg prefetch
// + single lgkm-only barrier per stage, vmcnt never drained).
// ---------------------------------------------------------------------------
__global__ __launch_bounds__(256, 3) void qkv_kernel(
    const float* __restrict__ enc,            // (M,128) fp32
    const unsigned short* __restrict__ WT,    // (3,512,128) bf16 n-major
    unsigned short* __restrict__ Qh,
    unsigned short* __restrict__ Kh,
    unsigned short* __restrict__ Vt)
{
  const int g = blockIdx.x;  // 0..1023
  const int nt = g & 3;      // head (consecutive g share mt -> L2 reuse of A)
  const int mt = g >> 2;     // 0..255
  const int t = threadIdx.x;
  const int lane = t & 63;
  const int w = t >> 6;
  const int quad = lane >> 4;
  const int l16 = lane & 15;

  __shared__ __align__(16) unsigned short Bld[2][128 * 72];   // 36864 B

  const int m0 = mt * 128, n0 = nt * 128;
  const int wm = (w >> 1) * 64, wn = (w & 1) * 64;

  const int b_row = t >> 3, b_col = (t & 7) << 3;  // B-stage: +32 rows per i

  // B prologue: s=0 -> regs -> Bld[0]; s=1 -> regs (held)
  u32x4 breg[4];
  {
    u32x4 breg0[4];
    #pragma unroll
    for (int i = 0; i < 4; ++i)
      breg0[i] = *(const u32x4*)(WT + (size_t)(n0 + b_row + i * 32) * HID + b_col);
    #pragma unroll
    for (int i = 0; i < 4; ++i)
      *(u32x4*)(Bld[0] + (b_row + i * 32) * 72 + b_col) = breg0[i];
  }
  #pragma unroll
  for (int i = 0; i < 4; ++i)   // s=1: z=0, kc=1
    breg[i] = *(const u32x4*)(WT + (size_t)(n0 + b_row + i * 32) * HID + 64 + b_col);

  // A-fragments: load + convert once from fp32 enc (64 VGPR, bit-identical
  // f2bf). Each frag = 8 consecutive k at (kc,kk,quad); row = wm+mi*16+l16.
  short8 qa[2][2][4];
  #pragma unroll
  for (int kc = 0; kc < 2; ++kc)
    #pragma unroll
    for (int kk = 0; kk < 2; ++kk)
      #pragma unroll
      for (int mi = 0; mi < 4; ++mi) {
        const float* src = enc + (size_t)(m0 + wm + mi * 16 + l16) * HID
                         + kc * 64 + kk * 32 + quad * 8;
        f32x4 a0 = *(const f32x4*)(src);
        f32x4 a1 = *(const f32x4*)(src + 4);
        short8 v;
        #pragma unroll
        for (int j = 0; j < 4; ++j) v[j] = (short)f2bf(a0[j]);
        #pragma unroll
        for (int j = 0; j < 4; ++j) v[4 + j] = (short)f2bf(a1[j]);
        qa[kc][kk][mi] = v;
      }

  asm volatile("s_waitcnt lgkmcnt(0)" ::: "memory");
  __builtin_amdgcn_s_barrier();

  f32x4 acc[4][4];
  #pragma unroll
  for (int s = 0; s < 6; ++s) {
    const int z = s >> 1, kc = s & 1, p = s & 1;
    if (kc == 0) {
      #pragma unroll
      for (int mi = 0; mi < 4; ++mi)
        #pragma unroll
        for (int ni = 0; ni < 4; ++ni)
          acc[mi][ni] = f32x4{0.f, 0.f, 0.f, 0.f};
    }

    const unsigned short* Br = Bld[p];
    #pragma unroll
    for (int kk = 0; kk < 2; ++kk) {
      short8 bb[4];
      #pragma unroll
      for (int ni = 0; ni < 4; ++ni)
        bb[ni] = *(const short8*)(Br + (wn + ni * 16 + l16) * 72 + kk * 32 + quad * 8);
      if (z < 2) {
        #pragma unroll
        for (int mi = 0; mi < 4; ++mi)
          #pragma unroll
          for (int ni = 0; ni < 4; ++ni)
            acc[mi][ni] = __builtin_amdgcn_mfma_f32_16x16x32_bf16(bb[ni], qa[kc][kk][mi], acc[mi][ni], 0, 0, 0);
      } else {
        #pragma unroll
        for (int mi = 0; mi < 4; ++mi)
          #pragma unroll
          for (int ni = 0; ni < 4; ++ni)
            acc[mi][ni] = __builtin_amdgcn_mfma_f32_16x16x32_bf16(qa[kc][kk][mi], bb[ni], acc[mi][ni], 0, 0, 0);
      }
    }

    if (s < 5) {
      // write prefetched B(s+1) into the idle buffer; issue loads for s+2
      unsigned short* Bw2 = Bld[p ^ 1];
      #pragma unroll
      for (int i = 0; i < 4; ++i)
        *(u32x4*)(Bw2 + (b_row + i * 32) * 72 + b_col) = breg[i];
      if (s < 4) {
        const int s2 = s + 2;
        const unsigned short* Wz = WT + (size_t)(s2 >> 1) * DPROJ * HID;
        #pragma unroll
        for (int i = 0; i < 4; ++i)
          breg[i] = *(const u32x4*)(Wz + (size_t)(n0 + b_row + i * 32) * HID + (s2 & 1) * 64 + b_col);
      }
      asm volatile("s_waitcnt lgkmcnt(0)" ::: "memory");
      __builtin_amdgcn_s_barrier();
    }

    if (kc == 1) {
      if (z < 2) {
        // D[n][m]: col(l16)=m-within-16, row(quad*4+r)=d-within-16
        unsigned short* outz = ((z == 0) ? Qh : Kh) + (size_t)nt * MTOT * HID;
        #pragma unroll
        for (int mi = 0; mi < 4; ++mi)
          #pragma unroll
          for (int ni = 0; ni < 4; ++ni) {
            int m = m0 + wm + mi * 16 + l16;
            int dbase = wn + ni * 16 + quad * 4;
            us4 pk;
            #pragma unroll
            for (int r = 0; r < 4; ++r) pk[r] = f2bf(acc[mi][ni][r]);
            *(us4*)(outz + (size_t)m * HID + dbase) = pk;
          }
      } else {
        // D[m][n]: reg axis = s (4 consecutive) -> Vt[(nt*B+b)*128 + d][s]
        #pragma unroll
        for (int mi = 0; mi < 4; ++mi)
          #pragma unroll
          for (int ni = 0; ni < 4; ++ni) {
            int row0 = m0 + wm + mi * 16 + quad * 4;
            int b = row0 >> 9, sres = row0 & 511;
            int d = wn + ni * 16 + l16;
            us4 pk;
            #pragma unroll
            for (int r = 0; r < 4; ++r) pk[r] = f2bf(acc[mi][ni][r]);
            *(us4*)(Vt + ((size_t)(nt * BATCH + b) * HID + d) * SLEN + sres) = pk;
          }
      }
    }
  }
}

// ---------------------------------------------------------------------------
// Kernel 2: flash attention — R13 (frozen; measured 55.0us, VGPR 60).
// ---------------------------------------------------------------------------
__global__ __launch_bounds__(512, 4) void attn_kernel(
    const unsigned short* __restrict__ Qh,   // (NH, M, 128)
    const unsigned short* __restrict__ Kh,   // (NH, M, 128)
    const unsigned short* __restrict__ Vt,   // (NH, B, 128, S)
    const unsigned int* __restrict__ mbits,  // (B, S, 16)
    unsigned short* __restrict__ ctx)        // (M, 512)
{
  const int lin = blockIdx.x;              // 0..1023
  const int work = (lin & 7) * 128 + (lin >> 3);
  const int qt = work & 3;
  const int h  = (work >> 2) & 3;
  const int b  = work >> 4;

  const int t = threadIdx.x;
  const int lane = t & 63;
  const int w = t >> 6;                    // 0..7
  const int quad = lane >> 4;
  const int l16 = lane & 15;

  __shared__ __align__(16) unsigned short Kld[2][64 * 136];   // 34816 B
  __shared__ __align__(16) unsigned short Vtld[2][128 * 72];  // 36864 B

  const int q0 = qt * 128;
  const size_t rowbase = (size_t)b * SLEN;
  const unsigned short* kbase0 = Kh + ((size_t)h * MTOT + rowbase) * HID;
  const unsigned short* vbase  = Vt + (size_t)(h * BATCH + b) * HID * SLEN;
  const unsigned int* mrow = mbits + (size_t)b * SLEN * 16;

  const int k_key = t >> 4, k_col = (t & 15) << 3;   // +32 keys at i=1
  const int v_d   = t >> 3, v_cc  = (t & 7) << 3;    // +64 d at i=1

  short8 qa[4];
  {
    const unsigned short* qbase =
        Qh + ((size_t)h * MTOT + rowbase + q0 + w * 16 + l16) * HID + quad * 8;
    #pragma unroll
    for (int kk = 0; kk < 4; ++kk)
      qa[kk] = *(const short8*)(qbase + kk * 32);
  }

  short8 ones;
  #pragma unroll
  for (int j = 0; j < 8; ++j) ones[j] = (short)0x3F80;  // bf16 1.0

  f32x4 oc[8], oc9;
  #pragma unroll
  for (int nd = 0; nd < 8; ++nd) oc[nd] = f32x4{0.f, 0.f, 0.f, 0.f};
  oc9 = f32x4{0.f, 0.f, 0.f, 0.f};

  // per-lane q-row is fixed: one mask base
  const unsigned int* mq = mrow + (size_t)(q0 + w * 16 + l16) * 16;

  // prologue: load chunk 0 -> regs -> buf0; load chunk 1 -> regs; barrier
  u32x4 kreg[2], vreg[2];
  #pragma unroll
  for (int i = 0; i < 2; ++i) {
    kreg[i] = *(const u32x4*)(kbase0 + (size_t)(k_key + i * 32) * HID + k_col);
    vreg[i] = *(const u32x4*)(vbase + (size_t)(v_d + i * 64) * SLEN + v_cc);
  }
  #pragma unroll
  for (int i = 0; i < 2; ++i) {
    *(u32x4*)(Kld[0] + (k_key + i * 32) * 136 + k_col) = kreg[i];
    *(u32x4*)(Vtld[0] + (v_d + i * 64) * 72 + v_cc) = vreg[i];
  }
  #pragma unroll
  for (int i = 0; i < 2; ++i) {
    kreg[i] = *(const u32x4*)(kbase0 + (size_t)(64 + k_key + i * 32) * HID + k_col);
    vreg[i] = *(const u32x4*)(vbase + (size_t)(v_d + i * 64) * SLEN + 64 + v_cc);
  }
  asm volatile("s_waitcnt lgkmcnt(0)" ::: "memory");
  __builtin_amdgcn_s_barrier();

  for (int c0 = 0; c0 < SLEN; c0 += 64) {
    const int p = (c0 >> 6) & 1;
    const unsigned short* Kr = Kld[p];
    const unsigned short* Vr = Vtld[p];

    // stage chunk c+1 (held in regs) into the other buffer; then issue
    // global loads for chunk c+2 (land during compute of c and c+1)
    if (c0 + 64 < SLEN) {
      unsigned short* Kw = Kld[p ^ 1];
      unsigned short* Vw = Vtld[p ^ 1];
      #pragma unroll
      for (int i = 0; i < 2; ++i) {
        *(u32x4*)(Kw + (k_key + i * 32) * 136 + k_col) = kreg[i];
        *(u32x4*)(Vw + (v_d + i * 64) * 72 + v_cc) = vreg[i];
      }
      if (c0 + 128 < SLEN) {
        #pragma unroll
        for (int i = 0; i < 2; ++i) {
          kreg[i] = *(const u32x4*)(kbase0 + (size_t)(c0 + 128 + k_key + i * 32) * HID + k_col);
          vreg[i] = *(const u32x4*)(vbase + (size_t)(v_d + i * 64) * SLEN + c0 + 128 + v_cc);
        }
      }
    }

    // mask bits: 64 keys for this lane's q-row (used after QK^T)
    u32x2 mw = *(const u32x2*)(mq + (c0 >> 5));

    // S^T = (Q K^T)^T via swapped operands: lane l16 = q, regs = keys
    f32x4 sc[4];
    #pragma unroll
    for (int ni = 0; ni < 4; ++ni) sc[ni] = f32x4{0.f, 0.f, 0.f, 0.f};
    __builtin_amdgcn_s_setprio(1);
    #pragma unroll
    for (int kk = 0; kk < 4; ++kk) {
      #pragma unroll
      for (int ni = 0; ni < 4; ++ni) {
        short8 bb = *(const short8*)(Kr + (ni * 16 + l16) * 136 + kk * 32 + quad * 8);
        sc[ni] = __builtin_amdgcn_mfma_f32_16x16x32_bf16(bb, qa[kk], sc[ni], 0, 0, 0);
      }
    }
    __builtin_amdgcn_s_setprio(0);

    // p = mask ? exp2(s) : 0, packed to bf16 pairs in-register
    unsigned int pk[4][2];
    #pragma unroll
    for (int ni = 0; ni < 4; ++ni) {
      unsigned wsel = (ni < 2) ? mw[0] : mw[1];
      float pp[4];
      #pragma unroll
      for (int r = 0; r < 4; ++r) {
        int bit = (ni & 1) * 16 + quad * 4 + r;
        float e = __builtin_amdgcn_exp2f(sc[ni][r]);   // raw v_exp_f32
        pp[r] = ((wsel >> bit) & 1u) ? e : 0.f;
      }
      asm("v_cvt_pk_bf16_f32 %0, %1, %2" : "=v"(pk[ni][0]) : "v"(pp[0]), "v"(pp[1]));
      asm("v_cvt_pk_bf16_f32 %0, %1, %2" : "=v"(pk[ni][1]) : "v"(pp[2]), "v"(pp[3]));
    }

    // O += P @ V ; rowsum += P @ 1 ; P A-frags assembled via permlane swaps
    #pragma unroll
    for (int kb = 0; kb < 2; ++kb) {
      unsigned int c0w = pk[kb * 2][0], c2w = pk[kb * 2 + 1][0];
      asm("v_permlane32_swap_b32 %0, %1" : "+v"(c0w), "+v"(c2w));
      asm("v_permlane16_swap_b32 %0, %1" : "+v"(c0w), "+v"(c2w));
      unsigned int c1w = pk[kb * 2][1], c3w = pk[kb * 2 + 1][1];
      asm("v_permlane32_swap_b32 %0, %1" : "+v"(c1w), "+v"(c3w));
      asm("v_permlane16_swap_b32 %0, %1" : "+v"(c1w), "+v"(c3w));
      short8 a = __builtin_bit_cast(short8, u32x4{c0w, c1w, c2w, c3w});
      __builtin_amdgcn_s_setprio(1);
      #pragma unroll
      for (int nd = 0; nd < 8; ++nd) {
        short8 bv = *(const short8*)(Vr + (nd * 16 + l16) * 72 + kb * 32 + quad * 8);
        oc[nd] = __builtin_amdgcn_mfma_f32_16x16x32_bf16(a, bv, oc[nd], 0, 0, 0);
      }
      oc9 = __builtin_amdgcn_mfma_f32_16x16x32_bf16(a, ones, oc9, 0, 0, 0);
      __builtin_amdgcn_s_setprio(0);
    }

    // one barrier per chunk: own LDS writes visible, then all waves align.
    // vmcnt NOT drained -> c+2 loads stay in flight across the barrier.
    if (c0 + 64 < SLEN) {
      asm volatile("s_waitcnt lgkmcnt(0)" ::: "memory");
      __builtin_amdgcn_s_barrier();
    }
  }

  // D[q][d] epilogue: rcp once per row, multiply
  float rcp[4];
  #pragma unroll
  for (int r = 0; r < 4; ++r) rcp[r] = __builtin_amdgcn_rcpf(oc9[r]);
  #pragma unroll
  for (int nd = 0; nd < 8; ++nd)
    #pragma unroll
    for (int r = 0; r < 4; ++r) {
      float val = oc[nd][r] * rcp[r];
      int row = q0 + w * 16 + quad * 4 + r;
      int col = h * HID + nd * 16 + l16;
      ctx[(rowbase + row) * DPROJ + col] = f2bf(val);
    }
}

// ---------------------------------------------------------------------------
// Kernel 3: output projection + residual + LayerNorm — R14 (frozen).
// ---------------------------------------------------------------------------
__global__ __launch_bounds__(256, 2) void oproj_ln_kernel(
    const unsigned short* __restrict__ ctx,   // (M,512) bf16
    const unsigned short* __restrict__ WoT,   // (128,512) bf16 n-major
    const float* __restrict__ enc,            // (M,128) fp32
    const float* __restrict__ gamma,
    const float* __restrict__ beta,
    float* __restrict__ out)                  // (M,128) fp32
{
  const int m0 = blockIdx.x * 64;
  const int t = threadIdx.x;
  const int lane = t & 63;
  const int w = t >> 6;
  const int quad = lane >> 4;
  const int l16 = lane & 15;

  __shared__ __align__(16) unsigned short Actx[2][64 * 72];   // 18432 B
  __shared__ __align__(16) unsigned short Bw[2][128 * 72];    // 36864 B

  const int a_row = t >> 3, a_col = (t & 7) << 3;   // +32 rows at i=1 (64 rows)
  const int b_row = t >> 3, b_col = (t & 7) << 3;   // +32 rows per i (128 rows)

  f32x4 acc[8];
  #pragma unroll
  for (int ni = 0; ni < 8; ++ni) acc[ni] = f32x4{0.f, 0.f, 0.f, 0.f};

  // prologue: (kc=0) -> regs -> buf0; (kc=1) -> regs; barrier
  u32x4 areg[2], breg[4];
  #pragma unroll
  for (int i = 0; i < 2; ++i)
    areg[i] = *(const u32x4*)(ctx + (size_t)(m0 + a_row + i * 32) * DPROJ + a_col);
  #pragma unroll
  for (int i = 0; i < 4; ++i)
    breg[i] = *(const u32x4*)(WoT + (size_t)(b_row + i * 32) * DPROJ + b_col);
  #pragma unroll
  for (int i = 0; i < 2; ++i)
    *(u32x4*)(Actx[0] + (a_row + i * 32) * 72 + a_col) = areg[i];
  #pragma unroll
  for (int i = 0; i < 4; ++i)
    *(u32x4*)(Bw[0] + (b_row + i * 32) * 72 + b_col) = breg[i];
  #pragma unroll
  for (int i = 0; i < 2; ++i)
    areg[i] = *(const u32x4*)(ctx + (size_t)(m0 + a_row + i * 32) * DPROJ + 64 + a_col);
  #pragma unroll
  for (int i = 0; i < 4; ++i)
    breg[i] = *(const u32x4*)(WoT + (size_t)(b_row + i * 32) * DPROJ + 64 + b_col);
  asm volatile("s_waitcnt lgkmcnt(0)" ::: "memory");
  __builtin_amdgcn_s_barrier();

  #pragma unroll
  for (int it = 0; it < 8; ++it) {
    const int p = it & 1;
    const unsigned short* Ar = Actx[p];
    const unsigned short* Br = Bw[p];
    #pragma unroll
    for (int kk = 0; kk < 2; ++kk) {
      short8 a = *(const short8*)(Ar + (w * 16 + l16) * 72 + kk * 32 + quad * 8);
      #pragma unroll
      for (int ni = 0; ni < 8; ++ni) {
        short8 bb = *(const short8*)(Br + (ni * 16 + l16) * 72 + kk * 32 + quad * 8);
        acc[ni] = __builtin_amdgcn_mfma_f32_16x16x32_bf16(a, bb, acc[ni], 0, 0, 0);
      }
    }
    if (it < 7) {
      unsigned short* Aw2 = Actx[p ^ 1];
      unsigned short* Bw2 = Bw[p ^ 1];
      #pragma unroll
      for (int i = 0; i < 2; ++i)
        *(u32x4*)(Aw2 + (a_row + i * 32) * 72 + a_col) = areg[i];
      #pragma unroll
      for (int i = 0; i < 4; ++i)
        *(u32x4*)(Bw2 + (b_row + i * 32) * 72 + b_col) = breg[i];
      if (it < 6) {
        const int kc2 = (it + 2) * 64;
        #pragma unroll
        for (int i = 0; i < 2; ++i)
          areg[i] = *(const u32x4*)(ctx + (size_t)(m0 + a_row + i * 32) * DPROJ + kc2 + a_col);
        #pragma unroll
        for (int i = 0; i < 4; ++i)
          breg[i] = *(const u32x4*)(WoT + (size_t)(b_row + i * 32) * DPROJ + kc2 + b_col);
      }
      asm volatile("s_waitcnt lgkmcnt(0)" ::: "memory");
      __builtin_amdgcn_s_barrier();
    }
  }

  float g[8], be[8];
  #pragma unroll
  for (int ni = 0; ni < 8; ++ni) {
    g[ni] = gamma[ni * 16 + l16];
    be[ni] = beta[ni * 16 + l16];
  }

  float val[8][4];
  #pragma unroll
  for (int r = 0; r < 4; ++r) {
    int m = m0 + w * 16 + quad * 4 + r;
    const float* erow = enc + (size_t)m * HID;
    float s = 0.f, s2 = 0.f;
    #pragma unroll
    for (int ni = 0; ni < 8; ++ni) {
      float v = acc[ni][r] + erow[ni * 16 + l16];
      val[ni][r] = v;
      s += v;
      s2 += v * v;
    }
    #pragma unroll
    for (int off = 1; off < 16; off <<= 1) {
      s  += __shfl_xor(s, off, 64);
      s2 += __shfl_xor(s2, off, 64);
    }
    float mean = s * (1.f / 128.f);
    float var = s2 * (1.f / 128.f) - mean * mean;
    float rstd = rsqrtf(var + 1e-6f);
    float* orow = out + (size_t)m * HID;
    #pragma unroll
    for (int ni = 0; ni < 8; ++ni)
      orow[ni * 16 + l16] = g[ni] * (val[ni][r] - mean) * rstd + be[ni];
  }
}

// ---------------------------------------------------------------------------
// ws layout (elements):
//   WT   : 3*512*128 shorts        WoT : 128*512 shorts
//   Qh   : 4*M*128 shorts          Kh  : 4*M*128 shorts
//   Vt   : 4*64*128*512 shorts     ctx : M*512 shorts
//   mbits: 64*512*16 u32
// ---------------------------------------------------------------------------
extern "C" void kernel_launch(void* const* d_in, const int* in_sizes, int n_in,
                              void* d_out, int out_size, void* d_ws, size_t ws_size,
                              hipStream_t stream) {
  const float* enc   = (const float*)d_in[0];
  const int*   mask  = (const int*)d_in[1];
  const float* Wq    = (const float*)d_in[2];
  const float* Wk    = (const float*)d_in[3];
  const float* Wv    = (const float*)d_in[4];
  const float* Wo    = (const float*)d_in[5];
  const float* gamma = (const float*)d_in[6];
  const float* beta  = (const float*)d_in[7];
  float* out = (float*)d_out;

  unsigned short* WT  = (unsigned short*)d_ws;
  unsigned short* WoT = WT + (size_t)3 * DPROJ * HID;
  unsigned short* Qh  = WoT + (size_t)HID * DPROJ;
  unsigned short* Kh  = Qh + (size_t)NHEAD * MTOT * HID;
  unsigned short* Vt  = Kh + (size_t)NHEAD * MTOT * HID;
  unsigned short* ctx = Vt + (size_t)NHEAD * MTOT * HID;
  unsigned int* mbits = (unsigned int*)(ctx + (size_t)MTOT * DPROJ);

  prep_kernel<<<2048, 256, 0, stream>>>(Wq, Wk, Wv, Wo, mask, WT, WoT, mbits);
  qkv_kernel<<<1024, 256, 0, stream>>>(enc, WT, Qh, Kh, Vt);
  attn_kernel<<<1024, 512, 0, stream>>>(Qh, Kh, Vt, mbits, ctx);
  oproj_ln_kernel<<<MTOT / 64, 256, 0, stream>>>(ctx, WoT, enc, gamma, beta, out);
}

// Round 9
// 225.284 us; speedup vs baseline: 1.2034x; 1.2034x over previous
//
#include <hip/hip_runtime.h>
#include <stdint.h>

#define BATCH 64
#define SLEN 512
#define HID 128
#define NHEAD 4
#define DPROJ 512            // HID * NHEAD
#define MTOT (BATCH * SLEN)  // 32768
#define SCALE 0.08838834764831845f
#define LOG2E 1.4426950408889634f

using short8 = __attribute__((ext_vector_type(8))) short;
using f32x4  = __attribute__((ext_vector_type(4))) float;
using u32x4  = __attribute__((ext_vector_type(4))) unsigned int;
using u32x2  = __attribute__((ext_vector_type(2))) unsigned int;
using us4    = __attribute__((ext_vector_type(4))) unsigned short;

__device__ __forceinline__ unsigned short f2bf(float f) {
  unsigned int u = __float_as_uint(f);
  u += 0x7fffu + ((u >> 16) & 1u);   // round-to-nearest-even
  return (unsigned short)(u >> 16);
}

// ---------------------------------------------------------------------------
// Kernel 0: prep — R19 = R4 structure + R17 vectorized mask pack.
// Blocks 0..1023: weight cast+transpose (Wq pre-scaled by SCALE*log2e).
// Blocks 1024..3071: enc fp32->bf16 (R4 path — qkv reads bf16 encb; the
//   R15/R18 in-kernel fp32 cast variants measured slower/spilled).
// Blocks 3072..4095: mask bit-pack, 16 B/lane int4 + 3-step shfl_xor
//   (bit-identical mbits; replaces 4 B/lane ballot — G13 ~2x on 67 MB).
// ---------------------------------------------------------------------------
__global__ __launch_bounds__(256) void prep_kernel(
    const float* __restrict__ Wq,
    const float* __restrict__ Wk,
    const float* __restrict__ Wv,
    const float* __restrict__ Wo,
    const float* __restrict__ enc,
    const int* __restrict__ mask,
    unsigned short* __restrict__ WT,
    unsigned short* __restrict__ WoT,
    unsigned short* __restrict__ encb,
    unsigned int* __restrict__ mbits)
{
  if (blockIdx.x < 1024) {
    int idx = blockIdx.x * 256 + threadIdx.x;
    int z = idx >> 16;
    int i = idx & 65535;
    if (z < 3) {
      const float* W = (z == 0) ? Wq : (z == 1) ? Wk : Wv;
      float scale = (z == 0) ? (SCALE * LOG2E) : 1.0f;  // exp2 form
      int k = i >> 9;
      int n = i & 511;
      WT[(size_t)z * 65536 + (size_t)n * 128 + k] = f2bf(W[i] * scale);
    } else {
      int k = i >> 7;
      int n = i & 127;
      WoT[(size_t)n * 512 + k] = f2bf(Wo[i]);
    }
  } else if (blockIdx.x < 3072) {
    size_t tid = (size_t)(blockIdx.x - 1024) * 256 + threadIdx.x;  // 0..524287
    const float* s = enc + tid * 8;
    f32x4 a0 = *(const f32x4*)(s);
    f32x4 a1 = *(const f32x4*)(s + 4);
    short8 v;
    #pragma unroll
    for (int j = 0; j < 4; ++j) v[j] = (short)f2bf(a0[j]);
    #pragma unroll
    for (int j = 0; j < 4; ++j) v[4 + j] = (short)f2bf(a1[j]);
    *(short8*)(encb + tid * 8) = v;
  } else {
    // mask -> bitmask: 1024 blocks x 4 waves x 16 tiles of 256 ints.
    const int l = threadIdx.x & 63;
    const int wv = threadIdx.x >> 6;
    const int m = blockIdx.x - 3072;
    #pragma unroll 4
    for (int it = 0; it < 16; ++it) {
      size_t tile = (size_t)m * 64 + (size_t)wv * 16 + it;
      u32x4 v = *(const u32x4*)(mask + tile * 256 + l * 4);
      unsigned nib = (v[0] ? 1u : 0u) | (v[1] ? 2u : 0u) |
                     (v[2] ? 4u : 0u) | (v[3] ? 8u : 0u);
      unsigned a  = nib | ((unsigned)__shfl_xor((int)nib, 1, 64) << 4);
      unsigned b2 = a   | ((unsigned)__shfl_xor((int)a,   2, 64) << 8);
      unsigned c  = b2  | ((unsigned)__shfl_xor((int)b2,  4, 64) << 16);
      if ((l & 7) == 0) mbits[tile * 8 + (l >> 3)] = c;
    }
  }
}

// ---------------------------------------------------------------------------
// Kernel 1: QKV projection — R14 (restored; was <55us inside R4's 222.9
// total, best measured qkv). encb bf16 input, A staged once in LDS,
// double-buffered B with reg prefetch, single lgkm-only barrier per stage,
// vmcnt never drained. (R18's regs-for-A spilled: VGPR 84 + 109 MB scratch.)
// ---------------------------------------------------------------------------
__global__ __launch_bounds__(256) void qkv_kernel(
    const unsigned short* __restrict__ encb,  // (M,128) bf16
    const unsigned short* __restrict__ WT,    // (3,512,128) bf16 n-major
    unsigned short* __restrict__ Qh,
    unsigned short* __restrict__ Kh,
    unsigned short* __restrict__ Vt)
{
  const int nt = blockIdx.x;   // 0..3 == head
  const int mt = blockIdx.y;   // 0..255
  const int t = threadIdx.x;
  const int lane = t & 63;
  const int w = t >> 6;
  const int quad = lane >> 4;
  const int l16 = lane & 15;

  __shared__ __align__(16) unsigned short Ald[128 * 136];     // 34816 B
  __shared__ __align__(16) unsigned short Bld[2][128 * 72];   // 36864 B

  const int m0 = mt * 128, n0 = nt * 128;
  const int wm = (w >> 1) * 64, wn = (w & 1) * 64;

  const int b_row = t >> 3, b_col = (t & 7) << 3;  // B-stage: +32 rows per i

  // prologue: A -> regs -> Ald; B(s=0) -> regs -> Bld[0]; B(s=1) -> regs
  {
    u32x4 areg[8];
    #pragma unroll
    for (int i = 0; i < 8; ++i) {
      int idx = i * 256 + t;
      areg[i] = *(const u32x4*)(encb + (size_t)(m0 + (idx >> 4)) * HID + ((idx & 15) << 3));
    }
    u32x4 breg0[4];
    #pragma unroll
    for (int i = 0; i < 4; ++i)
      breg0[i] = *(const u32x4*)(WT + (size_t)(n0 + b_row + i * 32) * HID + b_col);
    #pragma unroll
    for (int i = 0; i < 8; ++i) {
      int idx = i * 256 + t;
      *(u32x4*)(Ald + (idx >> 4) * 136 + ((idx & 15) << 3)) = areg[i];
    }
    #pragma unroll
    for (int i = 0; i < 4; ++i)
      *(u32x4*)(Bld[0] + (b_row + i * 32) * 72 + b_col) = breg0[i];
  }
  u32x4 breg[4];
  #pragma unroll
  for (int i = 0; i < 4; ++i)   // s=1: z=0, kc=1
    breg[i] = *(const u32x4*)(WT + (size_t)(n0 + b_row + i * 32) * HID + 64 + b_col);
  asm volatile("s_waitcnt lgkmcnt(0)" ::: "memory");
  __builtin_amdgcn_s_barrier();

  f32x4 acc[4][4];
  #pragma unroll
  for (int s = 0; s < 6; ++s) {
    const int z = s >> 1, kc = s & 1, p = s & 1;
    if (kc == 0) {
      #pragma unroll
      for (int mi = 0; mi < 4; ++mi)
        #pragma unroll
        for (int ni = 0; ni < 4; ++ni)
          acc[mi][ni] = f32x4{0.f, 0.f, 0.f, 0.f};
    }

    const unsigned short* Br = Bld[p];
    #pragma unroll
    for (int kk = 0; kk < 2; ++kk) {
      short8 a[4], bb[4];
      #pragma unroll
      for (int mi = 0; mi < 4; ++mi)
        a[mi] = *(const short8*)(Ald + (wm + mi * 16 + l16) * 136 + kc * 64 + kk * 32 + quad * 8);
      #pragma unroll
      for (int ni = 0; ni < 4; ++ni)
        bb[ni] = *(const short8*)(Br + (wn + ni * 16 + l16) * 72 + kk * 32 + quad * 8);
      if (z < 2) {
        #pragma unroll
        for (int mi = 0; mi < 4; ++mi)
          #pragma unroll
          for (int ni = 0; ni < 4; ++ni)
            acc[mi][ni] = __builtin_amdgcn_mfma_f32_16x16x32_bf16(bb[ni], a[mi], acc[mi][ni], 0, 0, 0);
      } else {
        #pragma unroll
        for (int mi = 0; mi < 4; ++mi)
          #pragma unroll
          for (int ni = 0; ni < 4; ++ni)
            acc[mi][ni] = __builtin_amdgcn_mfma_f32_16x16x32_bf16(a[mi], bb[ni], acc[mi][ni], 0, 0, 0);
      }
    }

    if (s < 5) {
      // write prefetched B(s+1) into the idle buffer; issue loads for s+2
      unsigned short* Bw2 = Bld[p ^ 1];
      #pragma unroll
      for (int i = 0; i < 4; ++i)
        *(u32x4*)(Bw2 + (b_row + i * 32) * 72 + b_col) = breg[i];
      if (s < 4) {
        const int s2 = s + 2;
        const unsigned short* Wz = WT + (size_t)(s2 >> 1) * DPROJ * HID;
        #pragma unroll
        for (int i = 0; i < 4; ++i)
          breg[i] = *(const u32x4*)(Wz + (size_t)(n0 + b_row + i * 32) * HID + (s2 & 1) * 64 + b_col);
      }
      asm volatile("s_waitcnt lgkmcnt(0)" ::: "memory");
      __builtin_amdgcn_s_barrier();
    }

    if (kc == 1) {
      if (z < 2) {
        // D[n][m]: col(l16)=m-within-16, row(quad*4+r)=d-within-16
        unsigned short* outz = ((z == 0) ? Qh : Kh) + (size_t)nt * MTOT * HID;
        #pragma unroll
        for (int mi = 0; mi < 4; ++mi)
          #pragma unroll
          for (int ni = 0; ni < 4; ++ni) {
            int m = m0 + wm + mi * 16 + l16;
            int dbase = wn + ni * 16 + quad * 4;
            us4 pk;
            #pragma unroll
            for (int r = 0; r < 4; ++r) pk[r] = f2bf(acc[mi][ni][r]);
            *(us4*)(outz + (size_t)m * HID + dbase) = pk;
          }
      } else {
        // D[m][n]: reg axis = s (4 consecutive) -> Vt[(nt*B+b)*128 + d][s]
        #pragma unroll
        for (int mi = 0; mi < 4; ++mi)
          #pragma unroll
          for (int ni = 0; ni < 4; ++ni) {
            int row0 = m0 + wm + mi * 16 + quad * 4;
            int b = row0 >> 9, sres = row0 & 511;
            int d = wn + ni * 16 + l16;
            us4 pk;
            #pragma unroll
            for (int r = 0; r < 4; ++r) pk[r] = f2bf(acc[mi][ni][r]);
            *(us4*)(Vt + ((size_t)(nt * BATCH + b) * HID + d) * SLEN + sres) = pk;
          }
      }
    }
  }
}

// ---------------------------------------------------------------------------
// Kernel 2: flash attention — R13 (frozen; measured 55.0us, VGPR 60).
// ---------------------------------------------------------------------------
__global__ __launch_bounds__(512, 4) void attn_kernel(
    const unsigned short* __restrict__ Qh,   // (NH, M, 128)
    const unsigned short* __restrict__ Kh,   // (NH, M, 128)
    const unsigned short* __restrict__ Vt,   // (NH, B, 128, S)
    const unsigned int* __restrict__ mbits,  // (B, S, 16)
    unsigned short* __restrict__ ctx)        // (M, 512)
{
  const int lin = blockIdx.x;              // 0..1023
  const int work = (lin & 7) * 128 + (lin >> 3);
  const int qt = work & 3;
  const int h  = (work >> 2) & 3;
  const int b  = work >> 4;

  const int t = threadIdx.x;
  const int lane = t & 63;
  const int w = t >> 6;                    // 0..7
  const int quad = lane >> 4;
  const int l16 = lane & 15;

  __shared__ __align__(16) unsigned short Kld[2][64 * 136];   // 34816 B
  __shared__ __align__(16) unsigned short Vtld[2][128 * 72];  // 36864 B

  const int q0 = qt * 128;
  const size_t rowbase = (size_t)b * SLEN;
  const unsigned short* kbase0 = Kh + ((size_t)h * MTOT + rowbase) * HID;
  const unsigned short* vbase  = Vt + (size_t)(h * BATCH + b) * HID * SLEN;
  const unsigned int* mrow = mbits + (size_t)b * SLEN * 16;

  const int k_key = t >> 4, k_col = (t & 15) << 3;   // +32 keys at i=1
  const int v_d   = t >> 3, v_cc  = (t & 7) << 3;    // +64 d at i=1

  short8 qa[4];
  {
    const unsigned short* qbase =
        Qh + ((size_t)h * MTOT + rowbase + q0 + w * 16 + l16) * HID + quad * 8;
    #pragma unroll
    for (int kk = 0; kk < 4; ++kk)
      qa[kk] = *(const short8*)(qbase + kk * 32);
  }

  short8 ones;
  #pragma unroll
  for (int j = 0; j < 8; ++j) ones[j] = (short)0x3F80;  // bf16 1.0

  f32x4 oc[8], oc9;
  #pragma unroll
  for (int nd = 0; nd < 8; ++nd) oc[nd] = f32x4{0.f, 0.f, 0.f, 0.f};
  oc9 = f32x4{0.f, 0.f, 0.f, 0.f};

  // per-lane q-row is fixed: one mask base
  const unsigned int* mq = mrow + (size_t)(q0 + w * 16 + l16) * 16;

  // prologue: load chunk 0 -> regs -> buf0; load chunk 1 -> regs; barrier
  u32x4 kreg[2], vreg[2];
  #pragma unroll
  for (int i = 0; i < 2; ++i) {
    kreg[i] = *(const u32x4*)(kbase0 + (size_t)(k_key + i * 32) * HID + k_col);
    vreg[i] = *(const u32x4*)(vbase + (size_t)(v_d + i * 64) * SLEN + v_cc);
  }
  #pragma unroll
  for (int i = 0; i < 2; ++i) {
    *(u32x4*)(Kld[0] + (k_key + i * 32) * 136 + k_col) = kreg[i];
    *(u32x4*)(Vtld[0] + (v_d + i * 64) * 72 + v_cc) = vreg[i];
  }
  #pragma unroll
  for (int i = 0; i < 2; ++i) {
    kreg[i] = *(const u32x4*)(kbase0 + (size_t)(64 + k_key + i * 32) * HID + k_col);
    vreg[i] = *(const u32x4*)(vbase + (size_t)(v_d + i * 64) * SLEN + 64 + v_cc);
  }
  asm volatile("s_waitcnt lgkmcnt(0)" ::: "memory");
  __builtin_amdgcn_s_barrier();

  for (int c0 = 0; c0 < SLEN; c0 += 64) {
    const int p = (c0 >> 6) & 1;
    const unsigned short* Kr = Kld[p];
    const unsigned short* Vr = Vtld[p];

    // stage chunk c+1 (held in regs) into the other buffer; then issue
    // global loads for chunk c+2 (land during compute of c and c+1)
    if (c0 + 64 < SLEN) {
      unsigned short* Kw = Kld[p ^ 1];
      unsigned short* Vw = Vtld[p ^ 1];
      #pragma unroll
      for (int i = 0; i < 2; ++i) {
        *(u32x4*)(Kw + (k_key + i * 32) * 136 + k_col) = kreg[i];
        *(u32x4*)(Vw + (v_d + i * 64) * 72 + v_cc) = vreg[i];
      }
      if (c0 + 128 < SLEN) {
        #pragma unroll
        for (int i = 0; i < 2; ++i) {
          kreg[i] = *(const u32x4*)(kbase0 + (size_t)(c0 + 128 + k_key + i * 32) * HID + k_col);
          vreg[i] = *(const u32x4*)(vbase + (size_t)(v_d + i * 64) * SLEN + c0 + 128 + v_cc);
        }
      }
    }

    // mask bits: 64 keys for this lane's q-row (used after QK^T)
    u32x2 mw = *(const u32x2*)(mq + (c0 >> 5));

    // S^T = (Q K^T)^T via swapped operands: lane l16 = q, regs = keys
    f32x4 sc[4];
    #pragma unroll
    for (int ni = 0; ni < 4; ++ni) sc[ni] = f32x4{0.f, 0.f, 0.f, 0.f};
    __builtin_amdgcn_s_setprio(1);
    #pragma unroll
    for (int kk = 0; kk < 4; ++kk) {
      #pragma unroll
      for (int ni = 0; ni < 4; ++ni) {
        short8 bb = *(const short8*)(Kr + (ni * 16 + l16) * 136 + kk * 32 + quad * 8);
        sc[ni] = __builtin_amdgcn_mfma_f32_16x16x32_bf16(bb, qa[kk], sc[ni], 0, 0, 0);
      }
    }
    __builtin_amdgcn_s_setprio(0);

    // p = mask ? exp2(s) : 0, packed to bf16 pairs in-register
    unsigned int pk[4][2];
    #pragma unroll
    for (int ni = 0; ni < 4; ++ni) {
      unsigned wsel = (ni < 2) ? mw[0] : mw[1];
      float pp[4];
      #pragma unroll
      for (int r = 0; r < 4; ++r) {
        int bit = (ni & 1) * 16 + quad * 4 + r;
        float e = __builtin_amdgcn_exp2f(sc[ni][r]);   // raw v_exp_f32
        pp[r] = ((wsel >> bit) & 1u) ? e : 0.f;
      }
      asm("v_cvt_pk_bf16_f32 %0, %1, %2" : "=v"(pk[ni][0]) : "v"(pp[0]), "v"(pp[1]));
      asm("v_cvt_pk_bf16_f32 %0, %1, %2" : "=v"(pk[ni][1]) : "v"(pp[2]), "v"(pp[3]));
    }

    // O += P @ V ; rowsum += P @ 1 ; P A-frags assembled via permlane swaps
    #pragma unroll
    for (int kb = 0; kb < 2; ++kb) {
      unsigned int c0w = pk[kb * 2][0], c2w = pk[kb * 2 + 1][0];
      asm("v_permlane32_swap_b32 %0, %1" : "+v"(c0w), "+v"(c2w));
      asm("v_permlane16_swap_b32 %0, %1" : "+v"(c0w), "+v"(c2w));
      unsigned int c1w = pk[kb * 2][1], c3w = pk[kb * 2 + 1][1];
      asm("v_permlane32_swap_b32 %0, %1" : "+v"(c1w), "+v"(c3w));
      asm("v_permlane16_swap_b32 %0, %1" : "+v"(c1w), "+v"(c3w));
      short8 a = __builtin_bit_cast(short8, u32x4{c0w, c1w, c2w, c3w});
      __builtin_amdgcn_s_setprio(1);
      #pragma unroll
      for (int nd = 0; nd < 8; ++nd) {
        short8 bv = *(const short8*)(Vr + (nd * 16 + l16) * 72 + kb * 32 + quad * 8);
        oc[nd] = __builtin_amdgcn_mfma_f32_16x16x32_bf16(a, bv, oc[nd], 0, 0, 0);
      }
      oc9 = __builtin_amdgcn_mfma_f32_16x16x32_bf16(a, ones, oc9, 0, 0, 0);
      __builtin_amdgcn_s_setprio(0);
    }

    // one barrier per chunk: own LDS writes visible, then all waves align.
    // vmcnt NOT drained -> c+2 loads stay in flight across the barrier.
    if (c0 + 64 < SLEN) {
      asm volatile("s_waitcnt lgkmcnt(0)" ::: "memory");
      __builtin_amdgcn_s_barrier();
    }
  }

  // D[q][d] epilogue: rcp once per row, multiply
  float rcp[4];
  #pragma unroll
  for (int r = 0; r < 4; ++r) rcp[r] = __builtin_amdgcn_rcpf(oc9[r]);
  #pragma unroll
  for (int nd = 0; nd < 8; ++nd)
    #pragma unroll
    for (int r = 0; r < 4; ++r) {
      float val = oc[nd][r] * rcp[r];
      int row = q0 + w * 16 + quad * 4 + r;
      int col = h * HID + nd * 16 + l16;
      ctx[(rowbase + row) * DPROJ + col] = f2bf(val);
    }
}

// ---------------------------------------------------------------------------
// Kernel 3: output projection + residual + LayerNorm — R14 (frozen).
// ---------------------------------------------------------------------------
__global__ __launch_bounds__(256, 2) void oproj_ln_kernel(
    const unsigned short* __restrict__ ctx,   // (M,512) bf16
    const unsigned short* __restrict__ WoT,   // (128,512) bf16 n-major
    const float* __restrict__ enc,            // (M,128) fp32
    const float* __restrict__ gamma,
    const float* __restrict__ beta,
    float* __restrict__ out)                  // (M,128) fp32
{
  const int m0 = blockIdx.x * 64;
  const int t = threadIdx.x;
  const int lane = t & 63;
  const int w = t >> 6;
  const int quad = lane >> 4;
  const int l16 = lane & 15;

  __shared__ __align__(16) unsigned short Actx[2][64 * 72];   // 18432 B
  __shared__ __align__(16) unsigned short Bw[2][128 * 72];    // 36864 B

  const int a_row = t >> 3, a_col = (t & 7) << 3;   // +32 rows at i=1 (64 rows)
  const int b_row = t >> 3, b_col = (t & 7) << 3;   // +32 rows per i (128 rows)

  f32x4 acc[8];
  #pragma unroll
  for (int ni = 0; ni < 8; ++ni) acc[ni] = f32x4{0.f, 0.f, 0.f, 0.f};

  // prologue: (kc=0) -> regs -> buf0; (kc=1) -> regs; barrier
  u32x4 areg[2], breg[4];
  #pragma unroll
  for (int i = 0; i < 2; ++i)
    areg[i] = *(const u32x4*)(ctx + (size_t)(m0 + a_row + i * 32) * DPROJ + a_col);
  #pragma unroll
  for (int i = 0; i < 4; ++i)
    breg[i] = *(const u32x4*)(WoT + (size_t)(b_row + i * 32) * DPROJ + b_col);
  #pragma unroll
  for (int i = 0; i < 2; ++i)
    *(u32x4*)(Actx[0] + (a_row + i * 32) * 72 + a_col) = areg[i];
  #pragma unroll
  for (int i = 0; i < 4; ++i)
    *(u32x4*)(Bw[0] + (b_row + i * 32) * 72 + b_col) = breg[i];
  #pragma unroll
  for (int i = 0; i < 2; ++i)
    areg[i] = *(const u32x4*)(ctx + (size_t)(m0 + a_row + i * 32) * DPROJ + 64 + a_col);
  #pragma unroll
  for (int i = 0; i < 4; ++i)
    breg[i] = *(const u32x4*)(WoT + (size_t)(b_row + i * 32) * DPROJ + 64 + b_col);
  asm volatile("s_waitcnt lgkmcnt(0)" ::: "memory");
  __builtin_amdgcn_s_barrier();

  #pragma unroll
  for (int it = 0; it < 8; ++it) {
    const int p = it & 1;
    const unsigned short* Ar = Actx[p];
    const unsigned short* Br = Bw[p];
    #pragma unroll
    for (int kk = 0; kk < 2; ++kk) {
      short8 a = *(const short8*)(Ar + (w * 16 + l16) * 72 + kk * 32 + quad * 8);
      #pragma unroll
      for (int ni = 0; ni < 8; ++ni) {
        short8 bb = *(const short8*)(Br + (ni * 16 + l16) * 72 + kk * 32 + quad * 8);
        acc[ni] = __builtin_amdgcn_mfma_f32_16x16x32_bf16(a, bb, acc[ni], 0, 0, 0);
      }
    }
    if (it < 7) {
      unsigned short* Aw2 = Actx[p ^ 1];
      unsigned short* Bw2 = Bw[p ^ 1];
      #pragma unroll
      for (int i = 0; i < 2; ++i)
        *(u32x4*)(Aw2 + (a_row + i * 32) * 72 + a_col) = areg[i];
      #pragma unroll
      for (int i = 0; i < 4; ++i)
        *(u32x4*)(Bw2 + (b_row + i * 32) * 72 + b_col) = breg[i];
      if (it < 6) {
        const int kc2 = (it + 2) * 64;
        #pragma unroll
        for (int i = 0; i < 2; ++i)
          areg[i] = *(const u32x4*)(ctx + (size_t)(m0 + a_row + i * 32) * DPROJ + kc2 + a_col);
        #pragma unroll
        for (int i = 0; i < 4; ++i)
          breg[i] = *(const u32x4*)(WoT + (size_t)(b_row + i * 32) * DPROJ + kc2 + b_col);
      }
      asm volatile("s_waitcnt lgkmcnt(0)" ::: "memory");
      __builtin_amdgcn_s_barrier();
    }
  }

  float g[8], be[8];
  #pragma unroll
  for (int ni = 0; ni < 8; ++ni) {
    g[ni] = gamma[ni * 16 + l16];
    be[ni] = beta[ni * 16 + l16];
  }

  float val[8][4];
  #pragma unroll
  for (int r = 0; r < 4; ++r) {
    int m = m0 + w * 16 + quad * 4 + r;
    const float* erow = enc + (size_t)m * HID;
    float s = 0.f, s2 = 0.f;
    #pragma unroll
    for (int ni = 0; ni < 8; ++ni) {
      float v = acc[ni][r] + erow[ni * 16 + l16];
      val[ni][r] = v;
      s += v;
      s2 += v * v;
    }
    #pragma unroll
    for (int off = 1; off < 16; off <<= 1) {
      s  += __shfl_xor(s, off, 64);
      s2 += __shfl_xor(s2, off, 64);
    }
    float mean = s * (1.f / 128.f);
    float var = s2 * (1.f / 128.f) - mean * mean;
    float rstd = rsqrtf(var + 1e-6f);
    float* orow = out + (size_t)m * HID;
    #pragma unroll
    for (int ni = 0; ni < 8; ++ni)
      orow[ni * 16 + l16] = g[ni] * (val[ni][r] - mean) * rstd + be[ni];
  }
}

// ---------------------------------------------------------------------------
// ws layout (elements):
//   WT   : 3*512*128 shorts        WoT : 128*512 shorts
//   Qh   : 4*M*128 shorts          Kh  : 4*M*128 shorts
//   Vt   : 4*64*128*512 shorts     ctx : M*512 shorts
//   encb : M*128 shorts            mbits: 64*512*16 u32
// ---------------------------------------------------------------------------
extern "C" void kernel_launch(void* const* d_in, const int* in_sizes, int n_in,
                              void* d_out, int out_size, void* d_ws, size_t ws_size,
                              hipStream_t stream) {
  const float* enc   = (const float*)d_in[0];
  const int*   mask  = (const int*)d_in[1];
  const float* Wq    = (const float*)d_in[2];
  const float* Wk    = (const float*)d_in[3];
  const float* Wv    = (const float*)d_in[4];
  const float* Wo    = (const float*)d_in[5];
  const float* gamma = (const float*)d_in[6];
  const float* beta  = (const float*)d_in[7];
  float* out = (float*)d_out;

  unsigned short* WT  = (unsigned short*)d_ws;
  unsigned short* WoT = WT + (size_t)3 * DPROJ * HID;
  unsigned short* Qh  = WoT + (size_t)HID * DPROJ;
  unsigned short* Kh  = Qh + (size_t)NHEAD * MTOT * HID;
  unsigned short* Vt  = Kh + (size_t)NHEAD * MTOT * HID;
  unsigned short* ctx = Vt + (size_t)NHEAD * MTOT * HID;
  unsigned short* encb = ctx + (size_t)MTOT * DPROJ;
  unsigned int* mbits = (unsigned int*)(encb + (size_t)MTOT * HID);

  prep_kernel<<<4096, 256, 0, stream>>>(Wq, Wk, Wv, Wo, enc, mask, WT, WoT, encb, mbits);
  qkv_kernel<<<dim3(4, 256), 256, 0, stream>>>(encb, WT, Qh, Kh, Vt);
  attn_kernel<<<1024, 512, 0, stream>>>(Qh, Kh, Vt, mbits, ctx);
  oproj_ln_kernel<<<MTOT / 64, 256, 0, stream>>>(ctx, WoT, enc, gamma, beta, out);
}

// Round 10
// 224.937 us; speedup vs baseline: 1.2053x; 1.0015x over previous
//
#include <hip/hip_runtime.h>
#include <stdint.h>

#define BATCH 64
#define SLEN 512
#define HID 128
#define NHEAD 4
#define DPROJ 512            // HID * NHEAD
#define MTOT (BATCH * SLEN)  // 32768
#define SCALE 0.08838834764831845f
#define LOG2E 1.4426950408889634f

using short8 = __attribute__((ext_vector_type(8))) short;
using f32x4  = __attribute__((ext_vector_type(4))) float;
using u32x4  = __attribute__((ext_vector_type(4))) unsigned int;
using u32x2  = __attribute__((ext_vector_type(2))) unsigned int;
using us4    = __attribute__((ext_vector_type(4))) unsigned short;

__device__ __forceinline__ unsigned short f2bf(float f) {
  unsigned int u = __float_as_uint(f);
  u += 0x7fffu + ((u >> 16) & 1u);   // round-to-nearest-even
  return (unsigned short)(u >> 16);
}

// ---------------------------------------------------------------------------
// Kernel 0: prep — R19 (frozen). Weights + enc cast + vectorized mask pack.
// ---------------------------------------------------------------------------
__global__ __launch_bounds__(256) void prep_kernel(
    const float* __restrict__ Wq,
    const float* __restrict__ Wk,
    const float* __restrict__ Wv,
    const float* __restrict__ Wo,
    const float* __restrict__ enc,
    const int* __restrict__ mask,
    unsigned short* __restrict__ WT,
    unsigned short* __restrict__ WoT,
    unsigned short* __restrict__ encb,
    unsigned int* __restrict__ mbits)
{
  if (blockIdx.x < 1024) {
    int idx = blockIdx.x * 256 + threadIdx.x;
    int z = idx >> 16;
    int i = idx & 65535;
    if (z < 3) {
      const float* W = (z == 0) ? Wq : (z == 1) ? Wk : Wv;
      float scale = (z == 0) ? (SCALE * LOG2E) : 1.0f;  // exp2 form
      int k = i >> 9;
      int n = i & 511;
      WT[(size_t)z * 65536 + (size_t)n * 128 + k] = f2bf(W[i] * scale);
    } else {
      int k = i >> 7;
      int n = i & 127;
      WoT[(size_t)n * 512 + k] = f2bf(Wo[i]);
    }
  } else if (blockIdx.x < 3072) {
    size_t tid = (size_t)(blockIdx.x - 1024) * 256 + threadIdx.x;  // 0..524287
    const float* s = enc + tid * 8;
    f32x4 a0 = *(const f32x4*)(s);
    f32x4 a1 = *(const f32x4*)(s + 4);
    short8 v;
    #pragma unroll
    for (int j = 0; j < 4; ++j) v[j] = (short)f2bf(a0[j]);
    #pragma unroll
    for (int j = 0; j < 4; ++j) v[4 + j] = (short)f2bf(a1[j]);
    *(short8*)(encb + tid * 8) = v;
  } else {
    // mask -> bitmask: 1024 blocks x 4 waves x 16 tiles of 256 ints.
    const int l = threadIdx.x & 63;
    const int wv = threadIdx.x >> 6;
    const int m = blockIdx.x - 3072;
    #pragma unroll 4
    for (int it = 0; it < 16; ++it) {
      size_t tile = (size_t)m * 64 + (size_t)wv * 16 + it;
      u32x4 v = *(const u32x4*)(mask + tile * 256 + l * 4);
      unsigned nib = (v[0] ? 1u : 0u) | (v[1] ? 2u : 0u) |
                     (v[2] ? 4u : 0u) | (v[3] ? 8u : 0u);
      unsigned a  = nib | ((unsigned)__shfl_xor((int)nib, 1, 64) << 4);
      unsigned b2 = a   | ((unsigned)__shfl_xor((int)a,   2, 64) << 8);
      unsigned c  = b2  | ((unsigned)__shfl_xor((int)b2,  4, 64) << 16);
      if ((l & 7) == 0) mbits[tile * 8 + (l >> 3)] = c;
    }
  }
}

// ---------------------------------------------------------------------------
// Kernel 1: QKV projection — R14 (frozen; best measured qkv).
// ---------------------------------------------------------------------------
__global__ __launch_bounds__(256) void qkv_kernel(
    const unsigned short* __restrict__ encb,  // (M,128) bf16
    const unsigned short* __restrict__ WT,    // (3,512,128) bf16 n-major
    unsigned short* __restrict__ Qh,
    unsigned short* __restrict__ Kh,
    unsigned short* __restrict__ Vt)
{
  const int nt = blockIdx.x;   // 0..3 == head
  const int mt = blockIdx.y;   // 0..255
  const int t = threadIdx.x;
  const int lane = t & 63;
  const int w = t >> 6;
  const int quad = lane >> 4;
  const int l16 = lane & 15;

  __shared__ __align__(16) unsigned short Ald[128 * 136];     // 34816 B
  __shared__ __align__(16) unsigned short Bld[2][128 * 72];   // 36864 B

  const int m0 = mt * 128, n0 = nt * 128;
  const int wm = (w >> 1) * 64, wn = (w & 1) * 64;

  const int b_row = t >> 3, b_col = (t & 7) << 3;  // B-stage: +32 rows per i

  // prologue: A -> regs -> Ald; B(s=0) -> regs -> Bld[0]; B(s=1) -> regs
  {
    u32x4 areg[8];
    #pragma unroll
    for (int i = 0; i < 8; ++i) {
      int idx = i * 256 + t;
      areg[i] = *(const u32x4*)(encb + (size_t)(m0 + (idx >> 4)) * HID + ((idx & 15) << 3));
    }
    u32x4 breg0[4];
    #pragma unroll
    for (int i = 0; i < 4; ++i)
      breg0[i] = *(const u32x4*)(WT + (size_t)(n0 + b_row + i * 32) * HID + b_col);
    #pragma unroll
    for (int i = 0; i < 8; ++i) {
      int idx = i * 256 + t;
      *(u32x4*)(Ald + (idx >> 4) * 136 + ((idx & 15) << 3)) = areg[i];
    }
    #pragma unroll
    for (int i = 0; i < 4; ++i)
      *(u32x4*)(Bld[0] + (b_row + i * 32) * 72 + b_col) = breg0[i];
  }
  u32x4 breg[4];
  #pragma unroll
  for (int i = 0; i < 4; ++i)   // s=1: z=0, kc=1
    breg[i] = *(const u32x4*)(WT + (size_t)(n0 + b_row + i * 32) * HID + 64 + b_col);
  asm volatile("s_waitcnt lgkmcnt(0)" ::: "memory");
  __builtin_amdgcn_s_barrier();

  f32x4 acc[4][4];
  #pragma unroll
  for (int s = 0; s < 6; ++s) {
    const int z = s >> 1, kc = s & 1, p = s & 1;
    if (kc == 0) {
      #pragma unroll
      for (int mi = 0; mi < 4; ++mi)
        #pragma unroll
        for (int ni = 0; ni < 4; ++ni)
          acc[mi][ni] = f32x4{0.f, 0.f, 0.f, 0.f};
    }

    const unsigned short* Br = Bld[p];
    #pragma unroll
    for (int kk = 0; kk < 2; ++kk) {
      short8 a[4], bb[4];
      #pragma unroll
      for (int mi = 0; mi < 4; ++mi)
        a[mi] = *(const short8*)(Ald + (wm + mi * 16 + l16) * 136 + kc * 64 + kk * 32 + quad * 8);
      #pragma unroll
      for (int ni = 0; ni < 4; ++ni)
        bb[ni] = *(const short8*)(Br + (wn + ni * 16 + l16) * 72 + kk * 32 + quad * 8);
      if (z < 2) {
        #pragma unroll
        for (int mi = 0; mi < 4; ++mi)
          #pragma unroll
          for (int ni = 0; ni < 4; ++ni)
            acc[mi][ni] = __builtin_amdgcn_mfma_f32_16x16x32_bf16(bb[ni], a[mi], acc[mi][ni], 0, 0, 0);
      } else {
        #pragma unroll
        for (int mi = 0; mi < 4; ++mi)
          #pragma unroll
          for (int ni = 0; ni < 4; ++ni)
            acc[mi][ni] = __builtin_amdgcn_mfma_f32_16x16x32_bf16(a[mi], bb[ni], acc[mi][ni], 0, 0, 0);
      }
    }

    if (s < 5) {
      // write prefetched B(s+1) into the idle buffer; issue loads for s+2
      unsigned short* Bw2 = Bld[p ^ 1];
      #pragma unroll
      for (int i = 0; i < 4; ++i)
        *(u32x4*)(Bw2 + (b_row + i * 32) * 72 + b_col) = breg[i];
      if (s < 4) {
        const int s2 = s + 2;
        const unsigned short* Wz = WT + (size_t)(s2 >> 1) * DPROJ * HID;
        #pragma unroll
        for (int i = 0; i < 4; ++i)
          breg[i] = *(const u32x4*)(Wz + (size_t)(n0 + b_row + i * 32) * HID + (s2 & 1) * 64 + b_col);
      }
      asm volatile("s_waitcnt lgkmcnt(0)" ::: "memory");
      __builtin_amdgcn_s_barrier();
    }

    if (kc == 1) {
      if (z < 2) {
        // D[n][m]: col(l16)=m-within-16, row(quad*4+r)=d-within-16
        unsigned short* outz = ((z == 0) ? Qh : Kh) + (size_t)nt * MTOT * HID;
        #pragma unroll
        for (int mi = 0; mi < 4; ++mi)
          #pragma unroll
          for (int ni = 0; ni < 4; ++ni) {
            int m = m0 + wm + mi * 16 + l16;
            int dbase = wn + ni * 16 + quad * 4;
            us4 pk;
            #pragma unroll
            for (int r = 0; r < 4; ++r) pk[r] = f2bf(acc[mi][ni][r]);
            *(us4*)(outz + (size_t)m * HID + dbase) = pk;
          }
      } else {
        // D[m][n]: reg axis = s (4 consecutive) -> Vt[(nt*B+b)*128 + d][s]
        #pragma unroll
        for (int mi = 0; mi < 4; ++mi)
          #pragma unroll
          for (int ni = 0; ni < 4; ++ni) {
            int row0 = m0 + wm + mi * 16 + quad * 4;
            int b = row0 >> 9, sres = row0 & 511;
            int d = wn + ni * 16 + l16;
            us4 pk;
            #pragma unroll
            for (int r = 0; r < 4; ++r) pk[r] = f2bf(acc[mi][ni][r]);
            *(us4*)(Vt + ((size_t)(nt * BATCH + b) * HID + d) * SLEN + sres) = pk;
          }
      }
    }
  }
}

// ---------------------------------------------------------------------------
// Kernel 2: flash attention — R20. R13 was ~84% LDS-pipe-bound: all 8 waves
// read IDENTICAL Kld/Vtld bytes (bb/bv addrs are wave-independent), so the
// same 32 KB was read 8x per chunk. R20: 256 thr / 4 waves / 32 q-rows per
// wave (mi=0,1) — every bb/bv ds_read_b128 feeds TWO mfmas. LDS instr per
// CU 9216 -> 5120. Differences from R1's failed attempt: in-register
// softmax (R12; no Pld) and launch_bounds(256,2) (R1's (256,3) made the
// compiler target 6 waves/EU at 84 VGPR and spill). K prefetch issued after
// staging, V prefetch after QK^T, to cap peak liveness (~185 VGPR est).
// Spill tell at post-mortem: WRITE_SIZE must stay ~32.8 MB.
// ---------------------------------------------------------------------------
__global__ __launch_bounds__(256, 2) void attn_kernel(
    const unsigned short* __restrict__ Qh,   // (NH, M, 128)
    const unsigned short* __restrict__ Kh,   // (NH, M, 128)
    const unsigned short* __restrict__ Vt,   // (NH, B, 128, S)
    const unsigned int* __restrict__ mbits,  // (B, S, 16)
    unsigned short* __restrict__ ctx)        // (M, 512)
{
  const int lin = blockIdx.x;              // 0..1023
  const int work = (lin & 7) * 128 + (lin >> 3);
  const int qt = work & 3;
  const int h  = (work >> 2) & 3;
  const int b  = work >> 4;

  const int t = threadIdx.x;               // 0..255
  const int lane = t & 63;
  const int w = t >> 6;                    // 0..3
  const int quad = lane >> 4;
  const int l16 = lane & 15;

  __shared__ __align__(16) unsigned short Kld[2][64 * 136];   // 34816 B
  __shared__ __align__(16) unsigned short Vtld[2][128 * 72];  // 36864 B

  const int q0 = qt * 128;
  const size_t rowbase = (size_t)b * SLEN;
  const unsigned short* kbase0 = Kh + ((size_t)h * MTOT + rowbase) * HID;
  const unsigned short* vbase  = Vt + (size_t)(h * BATCH + b) * HID * SLEN;
  const unsigned int* mrow = mbits + (size_t)b * SLEN * 16;

  const int k_key = t >> 4, k_col = (t & 15) << 3;   // +16 keys per i (4 i)
  const int v_d   = t >> 3, v_cc  = (t & 7) << 3;    // +32 d per i (4 i)

  // Q for this wave's 32 rows, held in registers (32 VGPR)
  short8 qa[2][4];
  #pragma unroll
  for (int mi = 0; mi < 2; ++mi) {
    const unsigned short* qbase =
        Qh + ((size_t)h * MTOT + rowbase + q0 + w * 32 + mi * 16 + l16) * HID + quad * 8;
    #pragma unroll
    for (int kk = 0; kk < 4; ++kk)
      qa[mi][kk] = *(const short8*)(qbase + kk * 32);
  }

  short8 ones;
  #pragma unroll
  for (int j = 0; j < 8; ++j) ones[j] = (short)0x3F80;  // bf16 1.0

  f32x4 oc[2][8], oc9[2];
  #pragma unroll
  for (int mi = 0; mi < 2; ++mi) {
    #pragma unroll
    for (int nd = 0; nd < 8; ++nd) oc[mi][nd] = f32x4{0.f, 0.f, 0.f, 0.f};
    oc9[mi] = f32x4{0.f, 0.f, 0.f, 0.f};
  }

  // per-lane q-row mask bases (one per mi)
  const unsigned int* mq0 = mrow + (size_t)(q0 + w * 32 + l16) * 16;
  const unsigned int* mq1 = mq0 + 256;   // +16 rows x 16 words

  // prologue: chunk0 -> regs -> buf0; chunk1 -> regs; barrier
  u32x4 kreg[4], vreg[4];
  #pragma unroll
  for (int i = 0; i < 4; ++i) {
    kreg[i] = *(const u32x4*)(kbase0 + (size_t)(k_key + i * 16) * HID + k_col);
    vreg[i] = *(const u32x4*)(vbase + (size_t)(v_d + i * 32) * SLEN + v_cc);
  }
  #pragma unroll
  for (int i = 0; i < 4; ++i) {
    *(u32x4*)(Kld[0] + (k_key + i * 16) * 136 + k_col) = kreg[i];
    *(u32x4*)(Vtld[0] + (v_d + i * 32) * 72 + v_cc) = vreg[i];
  }
  #pragma unroll
  for (int i = 0; i < 4; ++i) {
    kreg[i] = *(const u32x4*)(kbase0 + (size_t)(64 + k_key + i * 16) * HID + k_col);
    vreg[i] = *(const u32x4*)(vbase + (size_t)(v_d + i * 32) * SLEN + 64 + v_cc);
  }
  asm volatile("s_waitcnt lgkmcnt(0)" ::: "memory");
  __builtin_amdgcn_s_barrier();

  for (int c0 = 0; c0 < SLEN; c0 += 64) {
    const int p = (c0 >> 6) & 1;
    const unsigned short* Kr = Kld[p];
    const unsigned short* Vr = Vtld[p];

    // stage chunk c+1 into the idle buffer; issue K loads for c+2
    if (c0 + 64 < SLEN) {
      unsigned short* Kw = Kld[p ^ 1];
      unsigned short* Vw = Vtld[p ^ 1];
      #pragma unroll
      for (int i = 0; i < 4; ++i) {
        *(u32x4*)(Kw + (k_key + i * 16) * 136 + k_col) = kreg[i];
        *(u32x4*)(Vw + (v_d + i * 32) * 72 + v_cc) = vreg[i];
      }
      if (c0 + 128 < SLEN) {
        #pragma unroll
        for (int i = 0; i < 4; ++i)
          kreg[i] = *(const u32x4*)(kbase0 + (size_t)(c0 + 128 + k_key + i * 16) * HID + k_col);
      }
    }

    u32x2 mw0 = *(const u32x2*)(mq0 + (c0 >> 5));
    u32x2 mw1 = *(const u32x2*)(mq1 + (c0 >> 5));

    // S^T via swapped operands; each bb read feeds both mi
    f32x4 sc[2][4];
    #pragma unroll
    for (int mi = 0; mi < 2; ++mi)
      #pragma unroll
      for (int ni = 0; ni < 4; ++ni) sc[mi][ni] = f32x4{0.f, 0.f, 0.f, 0.f};
    __builtin_amdgcn_s_setprio(1);
    #pragma unroll
    for (int kk = 0; kk < 4; ++kk) {
      #pragma unroll
      for (int ni = 0; ni < 4; ++ni) {
        short8 bb = *(const short8*)(Kr + (ni * 16 + l16) * 136 + kk * 32 + quad * 8);
        sc[0][ni] = __builtin_amdgcn_mfma_f32_16x16x32_bf16(bb, qa[0][kk], sc[0][ni], 0, 0, 0);
        sc[1][ni] = __builtin_amdgcn_mfma_f32_16x16x32_bf16(bb, qa[1][kk], sc[1][ni], 0, 0, 0);
      }
    }
    __builtin_amdgcn_s_setprio(0);

    // V prefetch for c+2: latency covered by softmax + PV
    if (c0 + 128 < SLEN) {
      #pragma unroll
      for (int i = 0; i < 4; ++i)
        vreg[i] = *(const u32x4*)(vbase + (size_t)(v_d + i * 32) * SLEN + c0 + 128 + v_cc);
    }

    // softmax per row-group -> PV A-frags in registers (R12 path, per mi)
    short8 aF[2][2];
    #pragma unroll
    for (int mi = 0; mi < 2; ++mi) {
      u32x2 mw = (mi == 0) ? mw0 : mw1;
      unsigned int pk[4][2];
      #pragma unroll
      for (int ni = 0; ni < 4; ++ni) {
        unsigned wsel = (ni < 2) ? mw[0] : mw[1];
        float pp[4];
        #pragma unroll
        for (int r = 0; r < 4; ++r) {
          int bit = (ni & 1) * 16 + quad * 4 + r;
          float e = __builtin_amdgcn_exp2f(sc[mi][ni][r]);   // raw v_exp_f32
          pp[r] = ((wsel >> bit) & 1u) ? e : 0.f;
        }
        asm("v_cvt_pk_bf16_f32 %0, %1, %2" : "=v"(pk[ni][0]) : "v"(pp[0]), "v"(pp[1]));
        asm("v_cvt_pk_bf16_f32 %0, %1, %2" : "=v"(pk[ni][1]) : "v"(pp[2]), "v"(pp[3]));
      }
      #pragma unroll
      for (int kb = 0; kb < 2; ++kb) {
        unsigned int c0w = pk[kb * 2][0], c2w = pk[kb * 2 + 1][0];
        asm("v_permlane32_swap_b32 %0, %1" : "+v"(c0w), "+v"(c2w));
        asm("v_permlane16_swap_b32 %0, %1" : "+v"(c0w), "+v"(c2w));
        unsigned int c1w = pk[kb * 2][1], c3w = pk[kb * 2 + 1][1];
        asm("v_permlane32_swap_b32 %0, %1" : "+v"(c1w), "+v"(c3w));
        asm("v_permlane16_swap_b32 %0, %1" : "+v"(c1w), "+v"(c3w));
        aF[mi][kb] = __builtin_bit_cast(short8, u32x4{c0w, c1w, c2w, c3w});
      }
    }

    // O += P @ V ; rowsum += P @ 1 ; each bv read feeds both mi
    __builtin_amdgcn_s_setprio(1);
    #pragma unroll
    for (int kb = 0; kb < 2; ++kb) {
      #pragma unroll
      for (int nd = 0; nd < 8; ++nd) {
        short8 bv = *(const short8*)(Vr + (nd * 16 + l16) * 72 + kb * 32 + quad * 8);
        oc[0][nd] = __builtin_amdgcn_mfma_f32_16x16x32_bf16(aF[0][kb], bv, oc[0][nd], 0, 0, 0);
        oc[1][nd] = __builtin_amdgcn_mfma_f32_16x16x32_bf16(aF[1][kb], bv, oc[1][nd], 0, 0, 0);
      }
      oc9[0] = __builtin_amdgcn_mfma_f32_16x16x32_bf16(aF[0][kb], ones, oc9[0], 0, 0, 0);
      oc9[1] = __builtin_amdgcn_mfma_f32_16x16x32_bf16(aF[1][kb], ones, oc9[1], 0, 0, 0);
    }
    __builtin_amdgcn_s_setprio(0);

    // one barrier per chunk; vmcnt NOT drained (c+2 loads stay in flight)
    if (c0 + 64 < SLEN) {
      asm volatile("s_waitcnt lgkmcnt(0)" ::: "memory");
      __builtin_amdgcn_s_barrier();
    }
  }

  // epilogue: rcp once per row, multiply
  #pragma unroll
  for (int mi = 0; mi < 2; ++mi) {
    float rcp[4];
    #pragma unroll
    for (int r = 0; r < 4; ++r) rcp[r] = __builtin_amdgcn_rcpf(oc9[mi][r]);
    #pragma unroll
    for (int nd = 0; nd < 8; ++nd)
      #pragma unroll
      for (int r = 0; r < 4; ++r) {
        float val = oc[mi][nd][r] * rcp[r];
        int row = q0 + w * 32 + mi * 16 + quad * 4 + r;
        int col = h * HID + nd * 16 + l16;
        ctx[(rowbase + row) * DPROJ + col] = f2bf(val);
      }
  }
}

// ---------------------------------------------------------------------------
// Kernel 3: output projection + residual + LayerNorm — R14 (frozen).
// ---------------------------------------------------------------------------
__global__ __launch_bounds__(256, 2) void oproj_ln_kernel(
    const unsigned short* __restrict__ ctx,   // (M,512) bf16
    const unsigned short* __restrict__ WoT,   // (128,512) bf16 n-major
    const float* __restrict__ enc,            // (M,128) fp32
    const float* __restrict__ gamma,
    const float* __restrict__ beta,
    float* __restrict__ out)                  // (M,128) fp32
{
  const int m0 = blockIdx.x * 64;
  const int t = threadIdx.x;
  const int lane = t & 63;
  const int w = t >> 6;
  const int quad = lane >> 4;
  const int l16 = lane & 15;

  __shared__ __align__(16) unsigned short Actx[2][64 * 72];   // 18432 B
  __shared__ __align__(16) unsigned short Bw[2][128 * 72];    // 36864 B

  const int a_row = t >> 3, a_col = (t & 7) << 3;   // +32 rows at i=1 (64 rows)
  const int b_row = t >> 3, b_col = (t & 7) << 3;   // +32 rows per i (128 rows)

  f32x4 acc[8];
  #pragma unroll
  for (int ni = 0; ni < 8; ++ni) acc[ni] = f32x4{0.f, 0.f, 0.f, 0.f};

  // prologue: (kc=0) -> regs -> buf0; (kc=1) -> regs; barrier
  u32x4 areg[2], breg[4];
  #pragma unroll
  for (int i = 0; i < 2; ++i)
    areg[i] = *(const u32x4*)(ctx + (size_t)(m0 + a_row + i * 32) * DPROJ + a_col);
  #pragma unroll
  for (int i = 0; i < 4; ++i)
    breg[i] = *(const u32x4*)(WoT + (size_t)(b_row + i * 32) * DPROJ + b_col);
  #pragma unroll
  for (int i = 0; i < 2; ++i)
    *(u32x4*)(Actx[0] + (a_row + i * 32) * 72 + a_col) = areg[i];
  #pragma unroll
  for (int i = 0; i < 4; ++i)
    *(u32x4*)(Bw[0] + (b_row + i * 32) * 72 + b_col) = breg[i];
  #pragma unroll
  for (int i = 0; i < 2; ++i)
    areg[i] = *(const u32x4*)(ctx + (size_t)(m0 + a_row + i * 32) * DPROJ + 64 + a_col);
  #pragma unroll
  for (int i = 0; i < 4; ++i)
    breg[i] = *(const u32x4*)(WoT + (size_t)(b_row + i * 32) * DPROJ + 64 + b_col);
  asm volatile("s_waitcnt lgkmcnt(0)" ::: "memory");
  __builtin_amdgcn_s_barrier();

  #pragma unroll
  for (int it = 0; it < 8; ++it) {
    const int p = it & 1;
    const unsigned short* Ar = Actx[p];
    const unsigned short* Br = Bw[p];
    #pragma unroll
    for (int kk = 0; kk < 2; ++kk) {
      short8 a = *(const short8*)(Ar + (w * 16 + l16) * 72 + kk * 32 + quad * 8);
      #pragma unroll
      for (int ni = 0; ni < 8; ++ni) {
        short8 bb = *(const short8*)(Br + (ni * 16 + l16) * 72 + kk * 32 + quad * 8);
        acc[ni] = __builtin_amdgcn_mfma_f32_16x16x32_bf16(a, bb, acc[ni], 0, 0, 0);
      }
    }
    if (it < 7) {
      unsigned short* Aw2 = Actx[p ^ 1];
      unsigned short* Bw2 = Bw[p ^ 1];
      #pragma unroll
      for (int i = 0; i < 2; ++i)
        *(u32x4*)(Aw2 + (a_row + i * 32) * 72 + a_col) = areg[i];
      #pragma unroll
      for (int i = 0; i < 4; ++i)
        *(u32x4*)(Bw2 + (b_row + i * 32) * 72 + b_col) = breg[i];
      if (it < 6) {
        const int kc2 = (it + 2) * 64;
        #pragma unroll
        for (int i = 0; i < 2; ++i)
          areg[i] = *(const u32x4*)(ctx + (size_t)(m0 + a_row + i * 32) * DPROJ + kc2 + a_col);
        #pragma unroll
        for (int i = 0; i < 4; ++i)
          breg[i] = *(const u32x4*)(WoT + (size_t)(b_row + i * 32) * DPROJ + kc2 + b_col);
      }
      asm volatile("s_waitcnt lgkmcnt(0)" ::: "memory");
      __builtin_amdgcn_s_barrier();
    }
  }

  float g[8], be[8];
  #pragma unroll
  for (int ni = 0; ni < 8; ++ni) {
    g[ni] = gamma[ni * 16 + l16];
    be[ni] = beta[ni * 16 + l16];
  }

  float val[8][4];
  #pragma unroll
  for (int r = 0; r < 4; ++r) {
    int m = m0 + w * 16 + quad * 4 + r;
    const float* erow = enc + (size_t)m * HID;
    float s = 0.f, s2 = 0.f;
    #pragma unroll
    for (int ni = 0; ni < 8; ++ni) {
      float v = acc[ni][r] + erow[ni * 16 + l16];
      val[ni][r] = v;
      s += v;
      s2 += v * v;
    }
    #pragma unroll
    for (int off = 1; off < 16; off <<= 1) {
      s  += __shfl_xor(s, off, 64);
      s2 += __shfl_xor(s2, off, 64);
    }
    float mean = s * (1.f / 128.f);
    float var = s2 * (1.f / 128.f) - mean * mean;
    float rstd = rsqrtf(var + 1e-6f);
    float* orow = out + (size_t)m * HID;
    #pragma unroll
    for (int ni = 0; ni < 8; ++ni)
      orow[ni * 16 + l16] = g[ni] * (val[ni][r] - mean) * rstd + be[ni];
  }
}

// ---------------------------------------------------------------------------
// ws layout (elements):
//   WT   : 3*512*128 shorts        WoT : 128*512 shorts
//   Qh   : 4*M*128 shorts          Kh  : 4*M*128 shorts
//   Vt   : 4*64*128*512 shorts     ctx : M*512 shorts
//   encb : M*128 shorts            mbits: 64*512*16 u32
// ---------------------------------------------------------------------------
extern "C" void kernel_launch(void* const* d_in, const int* in_sizes, int n_in,
                              void* d_out, int out_size, void* d_ws, size_t ws_size,
                              hipStream_t stream) {
  const float* enc   = (const float*)d_in[0];
  const int*   mask  = (const int*)d_in[1];
  const float* Wq    = (const float*)d_in[2];
  const float* Wk    = (const float*)d_in[3];
  const float* Wv    = (const float*)d_in[4];
  const float* Wo    = (const float*)d_in[5];
  const float* gamma = (const float*)d_in[6];
  const float* beta  = (const float*)d_in[7];
  float* out = (float*)d_out;

  unsigned short* WT  = (unsigned short*)d_ws;
  unsigned short* WoT = WT + (size_t)3 * DPROJ * HID;
  unsigned short* Qh  = WoT + (size_t)HID * DPROJ;
  unsigned short* Kh  = Qh + (size_t)NHEAD * MTOT * HID;
  unsigned short* Vt  = Kh + (size_t)NHEAD * MTOT * HID;
  unsigned short* ctx = Vt + (size_t)NHEAD * MTOT * HID;
  unsigned short* encb = ctx + (size_t)MTOT * DPROJ;
  unsigned int* mbits = (unsigned int*)(encb + (size_t)MTOT * HID);

  prep_kernel<<<4096, 256, 0, stream>>>(Wq, Wk, Wv, Wo, enc, mask, WT, WoT, encb, mbits);
  qkv_kernel<<<dim3(4, 256), 256, 0, stream>>>(encb, WT, Qh, Kh, Vt);
  attn_kernel<<<1024, 256, 0, stream>>>(Qh, Kh, Vt, mbits, ctx);
  oproj_ln_kernel<<<MTOT / 64, 256, 0, stream>>>(ctx, WoT, enc, gamma, beta, out);
}

// Round 11
// 222.989 us; speedup vs baseline: 1.2158x; 1.0087x over previous
//
#include <hip/hip_runtime.h>
#include <stdint.h>

#define BATCH 64
#define SLEN 512
#define HID 128
#define NHEAD 4
#define DPROJ 512            // HID * NHEAD
#define MTOT (BATCH * SLEN)  // 32768
#define SCALE 0.08838834764831845f
#define LOG2E 1.4426950408889634f

using short8 = __attribute__((ext_vector_type(8))) short;
using f32x4  = __attribute__((ext_vector_type(4))) float;
using u32x4  = __attribute__((ext_vector_type(4))) unsigned int;
using u32x2  = __attribute__((ext_vector_type(2))) unsigned int;
using us4    = __attribute__((ext_vector_type(4))) unsigned short;

__device__ __forceinline__ unsigned short f2bf(float f) {
  unsigned int u = __float_as_uint(f);
  u += 0x7fffu + ((u >> 16) & 1u);   // round-to-nearest-even
  return (unsigned short)(u >> 16);
}

// ---------------------------------------------------------------------------
// Kernel 0: prep — R19 (frozen). Weights + enc cast + vectorized mask pack.
// ---------------------------------------------------------------------------
__global__ __launch_bounds__(256) void prep_kernel(
    const float* __restrict__ Wq,
    const float* __restrict__ Wk,
    const float* __restrict__ Wv,
    const float* __restrict__ Wo,
    const float* __restrict__ enc,
    const int* __restrict__ mask,
    unsigned short* __restrict__ WT,
    unsigned short* __restrict__ WoT,
    unsigned short* __restrict__ encb,
    unsigned int* __restrict__ mbits)
{
  if (blockIdx.x < 1024) {
    int idx = blockIdx.x * 256 + threadIdx.x;
    int z = idx >> 16;
    int i = idx & 65535;
    if (z < 3) {
      const float* W = (z == 0) ? Wq : (z == 1) ? Wk : Wv;
      float scale = (z == 0) ? (SCALE * LOG2E) : 1.0f;  // exp2 form
      int k = i >> 9;
      int n = i & 511;
      WT[(size_t)z * 65536 + (size_t)n * 128 + k] = f2bf(W[i] * scale);
    } else {
      int k = i >> 7;
      int n = i & 127;
      WoT[(size_t)n * 512 + k] = f2bf(Wo[i]);
    }
  } else if (blockIdx.x < 3072) {
    size_t tid = (size_t)(blockIdx.x - 1024) * 256 + threadIdx.x;  // 0..524287
    const float* s = enc + tid * 8;
    f32x4 a0 = *(const f32x4*)(s);
    f32x4 a1 = *(const f32x4*)(s + 4);
    short8 v;
    #pragma unroll
    for (int j = 0; j < 4; ++j) v[j] = (short)f2bf(a0[j]);
    #pragma unroll
    for (int j = 0; j < 4; ++j) v[4 + j] = (short)f2bf(a1[j]);
    *(short8*)(encb + tid * 8) = v;
  } else {
    // mask -> bitmask: 1024 blocks x 4 waves x 16 tiles of 256 ints.
    const int l = threadIdx.x & 63;
    const int wv = threadIdx.x >> 6;
    const int m = blockIdx.x - 3072;
    #pragma unroll 4
    for (int it = 0; it < 16; ++it) {
      size_t tile = (size_t)m * 64 + (size_t)wv * 16 + it;
      u32x4 v = *(const u32x4*)(mask + tile * 256 + l * 4);
      unsigned nib = (v[0] ? 1u : 0u) | (v[1] ? 2u : 0u) |
                     (v[2] ? 4u : 0u) | (v[3] ? 8u : 0u);
      unsigned a  = nib | ((unsigned)__shfl_xor((int)nib, 1, 64) << 4);
      unsigned b2 = a   | ((unsigned)__shfl_xor((int)a,   2, 64) << 8);
      unsigned c  = b2  | ((unsigned)__shfl_xor((int)b2,  4, 64) << 16);
      if ((l & 7) == 0) mbits[tile * 8 + (l >> 3)] = c;
    }
  }
}

// ---------------------------------------------------------------------------
// Kernel 1: QKV projection — R21 = R14 + XCD-aware block decode.
// R14's grid (4 heads, 256 mt) put the 4 blocks sharing one A-tile on 4
// DIFFERENT XCD L2s (linear id = head + mt*4, XCD = linear%8) -> A was
// re-fetched from HBM 4x (measured FETCH 33.6 MB vs 8.4 ideal), each load
// at ~900cy HBM latency in a latency-bound kernel. R21: 1-D grid, decode
// head=(lin>>3)&3, mt=(lin&7)+8*(lin>>5) — bijective, and the 4 same-mt
// blocks have lin == mt (mod 8) -> same XCD -> A hits L2 (~200cy) after
// the first fetch. Same pattern as attn's proven swizzle. GEMM body
// unchanged (byte-identical work per (head,mt)).
// ---------------------------------------------------------------------------
__global__ __launch_bounds__(256) void qkv_kernel(
    const unsigned short* __restrict__ encb,  // (M,128) bf16
    const unsigned short* __restrict__ WT,    // (3,512,128) bf16 n-major
    unsigned short* __restrict__ Qh,
    unsigned short* __restrict__ Kh,
    unsigned short* __restrict__ Vt)
{
  const int lin = blockIdx.x;            // 0..1023
  const int nt = (lin >> 3) & 3;         // head
  const int mt = (lin & 7) + 8 * (lin >> 5);   // 0..255
  const int t = threadIdx.x;
  const int lane = t & 63;
  const int w = t >> 6;
  const int quad = lane >> 4;
  const int l16 = lane & 15;

  __shared__ __align__(16) unsigned short Ald[128 * 136];     // 34816 B
  __shared__ __align__(16) unsigned short Bld[2][128 * 72];   // 36864 B

  const int m0 = mt * 128, n0 = nt * 128;
  const int wm = (w >> 1) * 64, wn = (w & 1) * 64;

  const int b_row = t >> 3, b_col = (t & 7) << 3;  // B-stage: +32 rows per i

  // prologue: A -> regs -> Ald; B(s=0) -> regs -> Bld[0]; B(s=1) -> regs
  {
    u32x4 areg[8];
    #pragma unroll
    for (int i = 0; i < 8; ++i) {
      int idx = i * 256 + t;
      areg[i] = *(const u32x4*)(encb + (size_t)(m0 + (idx >> 4)) * HID + ((idx & 15) << 3));
    }
    u32x4 breg0[4];
    #pragma unroll
    for (int i = 0; i < 4; ++i)
      breg0[i] = *(const u32x4*)(WT + (size_t)(n0 + b_row + i * 32) * HID + b_col);
    #pragma unroll
    for (int i = 0; i < 8; ++i) {
      int idx = i * 256 + t;
      *(u32x4*)(Ald + (idx >> 4) * 136 + ((idx & 15) << 3)) = areg[i];
    }
    #pragma unroll
    for (int i = 0; i < 4; ++i)
      *(u32x4*)(Bld[0] + (b_row + i * 32) * 72 + b_col) = breg0[i];
  }
  u32x4 breg[4];
  #pragma unroll
  for (int i = 0; i < 4; ++i)   // s=1: z=0, kc=1
    breg[i] = *(const u32x4*)(WT + (size_t)(n0 + b_row + i * 32) * HID + 64 + b_col);
  asm volatile("s_waitcnt lgkmcnt(0)" ::: "memory");
  __builtin_amdgcn_s_barrier();

  f32x4 acc[4][4];
  #pragma unroll
  for (int s = 0; s < 6; ++s) {
    const int z = s >> 1, kc = s & 1, p = s & 1;
    if (kc == 0) {
      #pragma unroll
      for (int mi = 0; mi < 4; ++mi)
        #pragma unroll
        for (int ni = 0; ni < 4; ++ni)
          acc[mi][ni] = f32x4{0.f, 0.f, 0.f, 0.f};
    }

    const unsigned short* Br = Bld[p];
    #pragma unroll
    for (int kk = 0; kk < 2; ++kk) {
      short8 a[4], bb[4];
      #pragma unroll
      for (int mi = 0; mi < 4; ++mi)
        a[mi] = *(const short8*)(Ald + (wm + mi * 16 + l16) * 136 + kc * 64 + kk * 32 + quad * 8);
      #pragma unroll
      for (int ni = 0; ni < 4; ++ni)
        bb[ni] = *(const short8*)(Br + (wn + ni * 16 + l16) * 72 + kk * 32 + quad * 8);
      if (z < 2) {
        #pragma unroll
        for (int mi = 0; mi < 4; ++mi)
          #pragma unroll
          for (int ni = 0; ni < 4; ++ni)
            acc[mi][ni] = __builtin_amdgcn_mfma_f32_16x16x32_bf16(bb[ni], a[mi], acc[mi][ni], 0, 0, 0);
      } else {
        #pragma unroll
        for (int mi = 0; mi < 4; ++mi)
          #pragma unroll
          for (int ni = 0; ni < 4; ++ni)
            acc[mi][ni] = __builtin_amdgcn_mfma_f32_16x16x32_bf16(a[mi], bb[ni], acc[mi][ni], 0, 0, 0);
      }
    }

    if (s < 5) {
      // write prefetched B(s+1) into the idle buffer; issue loads for s+2
      unsigned short* Bw2 = Bld[p ^ 1];
      #pragma unroll
      for (int i = 0; i < 4; ++i)
        *(u32x4*)(Bw2 + (b_row + i * 32) * 72 + b_col) = breg[i];
      if (s < 4) {
        const int s2 = s + 2;
        const unsigned short* Wz = WT + (size_t)(s2 >> 1) * DPROJ * HID;
        #pragma unroll
        for (int i = 0; i < 4; ++i)
          breg[i] = *(const u32x4*)(Wz + (size_t)(n0 + b_row + i * 32) * HID + (s2 & 1) * 64 + b_col);
      }
      asm volatile("s_waitcnt lgkmcnt(0)" ::: "memory");
      __builtin_amdgcn_s_barrier();
    }

    if (kc == 1) {
      if (z < 2) {
        // D[n][m]: col(l16)=m-within-16, row(quad*4+r)=d-within-16
        unsigned short* outz = ((z == 0) ? Qh : Kh) + (size_t)nt * MTOT * HID;
        #pragma unroll
        for (int mi = 0; mi < 4; ++mi)
          #pragma unroll
          for (int ni = 0; ni < 4; ++ni) {
            int m = m0 + wm + mi * 16 + l16;
            int dbase = wn + ni * 16 + quad * 4;
            us4 pk;
            #pragma unroll
            for (int r = 0; r < 4; ++r) pk[r] = f2bf(acc[mi][ni][r]);
            *(us4*)(outz + (size_t)m * HID + dbase) = pk;
          }
      } else {
        // D[m][n]: reg axis = s (4 consecutive) -> Vt[(nt*B+b)*128 + d][s]
        #pragma unroll
        for (int mi = 0; mi < 4; ++mi)
          #pragma unroll
          for (int ni = 0; ni < 4; ++ni) {
            int row0 = m0 + wm + mi * 16 + quad * 4;
            int b = row0 >> 9, sres = row0 & 511;
            int d = wn + ni * 16 + l16;
            us4 pk;
            #pragma unroll
            for (int r = 0; r < 4; ++r) pk[r] = f2bf(acc[mi][ni][r]);
            *(us4*)(Vt + ((size_t)(nt * BATCH + b) * HID + d) * SLEN + sres) = pk;
          }
      }
    }
  }
}

// ---------------------------------------------------------------------------
// Kernel 2: flash attention — R20 (frozen; 55.0us, VGPR 116, conflicts
// halved vs R13; equal time -> R13's LDS-throughput theory refuted, chunk
// critical-path-bound).
// ---------------------------------------------------------------------------
__global__ __launch_bounds__(256, 2) void attn_kernel(
    const unsigned short* __restrict__ Qh,   // (NH, M, 128)
    const unsigned short* __restrict__ Kh,   // (NH, M, 128)
    const unsigned short* __restrict__ Vt,   // (NH, B, 128, S)
    const unsigned int* __restrict__ mbits,  // (B, S, 16)
    unsigned short* __restrict__ ctx)        // (M, 512)
{
  const int lin = blockIdx.x;              // 0..1023
  const int work = (lin & 7) * 128 + (lin >> 3);
  const int qt = work & 3;
  const int h  = (work >> 2) & 3;
  const int b  = work >> 4;

  const int t = threadIdx.x;               // 0..255
  const int lane = t & 63;
  const int w = t >> 6;                    // 0..3
  const int quad = lane >> 4;
  const int l16 = lane & 15;

  __shared__ __align__(16) unsigned short Kld[2][64 * 136];   // 34816 B
  __shared__ __align__(16) unsigned short Vtld[2][128 * 72];  // 36864 B

  const int q0 = qt * 128;
  const size_t rowbase = (size_t)b * SLEN;
  const unsigned short* kbase0 = Kh + ((size_t)h * MTOT + rowbase) * HID;
  const unsigned short* vbase  = Vt + (size_t)(h * BATCH + b) * HID * SLEN;
  const unsigned int* mrow = mbits + (size_t)b * SLEN * 16;

  const int k_key = t >> 4, k_col = (t & 15) << 3;   // +16 keys per i (4 i)
  const int v_d   = t >> 3, v_cc  = (t & 7) << 3;    // +32 d per i (4 i)

  // Q for this wave's 32 rows, held in registers (32 VGPR)
  short8 qa[2][4];
  #pragma unroll
  for (int mi = 0; mi < 2; ++mi) {
    const unsigned short* qbase =
        Qh + ((size_t)h * MTOT + rowbase + q0 + w * 32 + mi * 16 + l16) * HID + quad * 8;
    #pragma unroll
    for (int kk = 0; kk < 4; ++kk)
      qa[mi][kk] = *(const short8*)(qbase + kk * 32);
  }

  short8 ones;
  #pragma unroll
  for (int j = 0; j < 8; ++j) ones[j] = (short)0x3F80;  // bf16 1.0

  f32x4 oc[2][8], oc9[2];
  #pragma unroll
  for (int mi = 0; mi < 2; ++mi) {
    #pragma unroll
    for (int nd = 0; nd < 8; ++nd) oc[mi][nd] = f32x4{0.f, 0.f, 0.f, 0.f};
    oc9[mi] = f32x4{0.f, 0.f, 0.f, 0.f};
  }

  // per-lane q-row mask bases (one per mi)
  const unsigned int* mq0 = mrow + (size_t)(q0 + w * 32 + l16) * 16;
  const unsigned int* mq1 = mq0 + 256;   // +16 rows x 16 words

  // prologue: chunk0 -> regs -> buf0; chunk1 -> regs; barrier
  u32x4 kreg[4], vreg[4];
  #pragma unroll
  for (int i = 0; i < 4; ++i) {
    kreg[i] = *(const u32x4*)(kbase0 + (size_t)(k_key + i * 16) * HID + k_col);
    vreg[i] = *(const u32x4*)(vbase + (size_t)(v_d + i * 32) * SLEN + v_cc);
  }
  #pragma unroll
  for (int i = 0; i < 4; ++i) {
    *(u32x4*)(Kld[0] + (k_key + i * 16) * 136 + k_col) = kreg[i];
    *(u32x4*)(Vtld[0] + (v_d + i * 32) * 72 + v_cc) = vreg[i];
  }
  #pragma unroll
  for (int i = 0; i < 4; ++i) {
    kreg[i] = *(const u32x4*)(kbase0 + (size_t)(64 + k_key + i * 16) * HID + k_col);
    vreg[i] = *(const u32x4*)(vbase + (size_t)(v_d + i * 32) * SLEN + 64 + v_cc);
  }
  asm volatile("s_waitcnt lgkmcnt(0)" ::: "memory");
  __builtin_amdgcn_s_barrier();

  for (int c0 = 0; c0 < SLEN; c0 += 64) {
    const int p = (c0 >> 6) & 1;
    const unsigned short* Kr = Kld[p];
    const unsigned short* Vr = Vtld[p];

    // stage chunk c+1 into the idle buffer; issue K loads for c+2
    if (c0 + 64 < SLEN) {
      unsigned short* Kw = Kld[p ^ 1];
      unsigned short* Vw = Vtld[p ^ 1];
      #pragma unroll
      for (int i = 0; i < 4; ++i) {
        *(u32x4*)(Kw + (k_key + i * 16) * 136 + k_col) = kreg[i];
        *(u32x4*)(Vw + (v_d + i * 32) * 72 + v_cc) = vreg[i];
      }
      if (c0 + 128 < SLEN) {
        #pragma unroll
        for (int i = 0; i < 4; ++i)
          kreg[i] = *(const u32x4*)(kbase0 + (size_t)(c0 + 128 + k_key + i * 16) * HID + k_col);
      }
    }

    u32x2 mw0 = *(const u32x2*)(mq0 + (c0 >> 5));
    u32x2 mw1 = *(const u32x2*)(mq1 + (c0 >> 5));

    // S^T via swapped operands; each bb read feeds both mi
    f32x4 sc[2][4];
    #pragma unroll
    for (int mi = 0; mi < 2; ++mi)
      #pragma unroll
      for (int ni = 0; ni < 4; ++ni) sc[mi][ni] = f32x4{0.f, 0.f, 0.f, 0.f};
    __builtin_amdgcn_s_setprio(1);
    #pragma unroll
    for (int kk = 0; kk < 4; ++kk) {
      #pragma unroll
      for (int ni = 0; ni < 4; ++ni) {
        short8 bb = *(const short8*)(Kr + (ni * 16 + l16) * 136 + kk * 32 + quad * 8);
        sc[0][ni] = __builtin_amdgcn_mfma_f32_16x16x32_bf16(bb, qa[0][kk], sc[0][ni], 0, 0, 0);
        sc[1][ni] = __builtin_amdgcn_mfma_f32_16x16x32_bf16(bb, qa[1][kk], sc[1][ni], 0, 0, 0);
      }
    }
    __builtin_amdgcn_s_setprio(0);

    // V prefetch for c+2: latency covered by softmax + PV
    if (c0 + 128 < SLEN) {
      #pragma unroll
      for (int i = 0; i < 4; ++i)
        vreg[i] = *(const u32x4*)(vbase + (size_t)(v_d + i * 32) * SLEN + c0 + 128 + v_cc);
    }

    // softmax per row-group -> PV A-frags in registers (R12 path, per mi)
    short8 aF[2][2];
    #pragma unroll
    for (int mi = 0; mi < 2; ++mi) {
      u32x2 mw = (mi == 0) ? mw0 : mw1;
      unsigned int pk[4][2];
      #pragma unroll
      for (int ni = 0; ni < 4; ++ni) {
        unsigned wsel = (ni < 2) ? mw[0] : mw[1];
        float pp[4];
        #pragma unroll
        for (int r = 0; r < 4; ++r) {
          int bit = (ni & 1) * 16 + quad * 4 + r;
          float e = __builtin_amdgcn_exp2f(sc[mi][ni][r]);   // raw v_exp_f32
          pp[r] = ((wsel >> bit) & 1u) ? e : 0.f;
        }
        asm("v_cvt_pk_bf16_f32 %0, %1, %2" : "=v"(pk[ni][0]) : "v"(pp[0]), "v"(pp[1]));
        asm("v_cvt_pk_bf16_f32 %0, %1, %2" : "=v"(pk[ni][1]) : "v"(pp[2]), "v"(pp[3]));
      }
      #pragma unroll
      for (int kb = 0; kb < 2; ++kb) {
        unsigned int c0w = pk[kb * 2][0], c2w = pk[kb * 2 + 1][0];
        asm("v_permlane32_swap_b32 %0, %1" : "+v"(c0w), "+v"(c2w));
        asm("v_permlane16_swap_b32 %0, %1" : "+v"(c0w), "+v"(c2w));
        unsigned int c1w = pk[kb * 2][1], c3w = pk[kb * 2 + 1][1];
        asm("v_permlane32_swap_b32 %0, %1" : "+v"(c1w), "+v"(c3w));
        asm("v_permlane16_swap_b32 %0, %1" : "+v"(c1w), "+v"(c3w));
        aF[mi][kb] = __builtin_bit_cast(short8, u32x4{c0w, c1w, c2w, c3w});
      }
    }

    // O += P @ V ; rowsum += P @ 1 ; each bv read feeds both mi
    __builtin_amdgcn_s_setprio(1);
    #pragma unroll
    for (int kb = 0; kb < 2; ++kb) {
      #pragma unroll
      for (int nd = 0; nd < 8; ++nd) {
        short8 bv = *(const short8*)(Vr + (nd * 16 + l16) * 72 + kb * 32 + quad * 8);
        oc[0][nd] = __builtin_amdgcn_mfma_f32_16x16x32_bf16(aF[0][kb], bv, oc[0][nd], 0, 0, 0);
        oc[1][nd] = __builtin_amdgcn_mfma_f32_16x16x32_bf16(aF[1][kb], bv, oc[1][nd], 0, 0, 0);
      }
      oc9[0] = __builtin_amdgcn_mfma_f32_16x16x32_bf16(aF[0][kb], ones, oc9[0], 0, 0, 0);
      oc9[1] = __builtin_amdgcn_mfma_f32_16x16x32_bf16(aF[1][kb], ones, oc9[1], 0, 0, 0);
    }
    __builtin_amdgcn_s_setprio(0);

    // one barrier per chunk; vmcnt NOT drained (c+2 loads stay in flight)
    if (c0 + 64 < SLEN) {
      asm volatile("s_waitcnt lgkmcnt(0)" ::: "memory");
      __builtin_amdgcn_s_barrier();
    }
  }

  // epilogue: rcp once per row, multiply
  #pragma unroll
  for (int mi = 0; mi < 2; ++mi) {
    float rcp[4];
    #pragma unroll
    for (int r = 0; r < 4; ++r) rcp[r] = __builtin_amdgcn_rcpf(oc9[mi][r]);
    #pragma unroll
    for (int nd = 0; nd < 8; ++nd)
      #pragma unroll
      for (int r = 0; r < 4; ++r) {
        float val = oc[mi][nd][r] * rcp[r];
        int row = q0 + w * 32 + mi * 16 + quad * 4 + r;
        int col = h * HID + nd * 16 + l16;
        ctx[(rowbase + row) * DPROJ + col] = f2bf(val);
      }
  }
}

// ---------------------------------------------------------------------------
// Kernel 3: output projection + residual + LayerNorm — R14 (frozen).
// ---------------------------------------------------------------------------
__global__ __launch_bounds__(256, 2) void oproj_ln_kernel(
    const unsigned short* __restrict__ ctx,   // (M,512) bf16
    const unsigned short* __restrict__ WoT,   // (128,512) bf16 n-major
    const float* __restrict__ enc,            // (M,128) fp32
    const float* __restrict__ gamma,
    const float* __restrict__ beta,
    float* __restrict__ out)                  // (M,128) fp32
{
  const int m0 = blockIdx.x * 64;
  const int t = threadIdx.x;
  const int lane = t & 63;
  const int w = t >> 6;
  const int quad = lane >> 4;
  const int l16 = lane & 15;

  __shared__ __align__(16) unsigned short Actx[2][64 * 72];   // 18432 B
  __shared__ __align__(16) unsigned short Bw[2][128 * 72];    // 36864 B

  const int a_row = t >> 3, a_col = (t & 7) << 3;   // +32 rows at i=1 (64 rows)
  const int b_row = t >> 3, b_col = (t & 7) << 3;   // +32 rows per i (128 rows)

  f32x4 acc[8];
  #pragma unroll
  for (int ni = 0; ni < 8; ++ni) acc[ni] = f32x4{0.f, 0.f, 0.f, 0.f};

  // prologue: (kc=0) -> regs -> buf0; (kc=1) -> regs; barrier
  u32x4 areg[2], breg[4];
  #pragma unroll
  for (int i = 0; i < 2; ++i)
    areg[i] = *(const u32x4*)(ctx + (size_t)(m0 + a_row + i * 32) * DPROJ + a_col);
  #pragma unroll
  for (int i = 0; i < 4; ++i)
    breg[i] = *(const u32x4*)(WoT + (size_t)(b_row + i * 32) * DPROJ + b_col);
  #pragma unroll
  for (int i = 0; i < 2; ++i)
    *(u32x4*)(Actx[0] + (a_row + i * 32) * 72 + a_col) = areg[i];
  #pragma unroll
  for (int i = 0; i < 4; ++i)
    *(u32x4*)(Bw[0] + (b_row + i * 32) * 72 + b_col) = breg[i];
  #pragma unroll
  for (int i = 0; i < 2; ++i)
    areg[i] = *(const u32x4*)(ctx + (size_t)(m0 + a_row + i * 32) * DPROJ + 64 + a_col);
  #pragma unroll
  for (int i = 0; i < 4; ++i)
    breg[i] = *(const u32x4*)(WoT + (size_t)(b_row + i * 32) * DPROJ + 64 + b_col);
  asm volatile("s_waitcnt lgkmcnt(0)" ::: "memory");
  __builtin_amdgcn_s_barrier();

  #pragma unroll
  for (int it = 0; it < 8; ++it) {
    const int p = it & 1;
    const unsigned short* Ar = Actx[p];
    const unsigned short* Br = Bw[p];
    #pragma unroll
    for (int kk = 0; kk < 2; ++kk) {
      short8 a = *(const short8*)(Ar + (w * 16 + l16) * 72 + kk * 32 + quad * 8);
      #pragma unroll
      for (int ni = 0; ni < 8; ++ni) {
        short8 bb = *(const short8*)(Br + (ni * 16 + l16) * 72 + kk * 32 + quad * 8);
        acc[ni] = __builtin_amdgcn_mfma_f32_16x16x32_bf16(a, bb, acc[ni], 0, 0, 0);
      }
    }
    if (it < 7) {
      unsigned short* Aw2 = Actx[p ^ 1];
      unsigned short* Bw2 = Bw[p ^ 1];
      #pragma unroll
      for (int i = 0; i < 2; ++i)
        *(u32x4*)(Aw2 + (a_row + i * 32) * 72 + a_col) = areg[i];
      #pragma unroll
      for (int i = 0; i < 4; ++i)
        *(u32x4*)(Bw2 + (b_row + i * 32) * 72 + b_col) = breg[i];
      if (it < 6) {
        const int kc2 = (it + 2) * 64;
        #pragma unroll
        for (int i = 0; i < 2; ++i)
          areg[i] = *(const u32x4*)(ctx + (size_t)(m0 + a_row + i * 32) * DPROJ + kc2 + a_col);
        #pragma unroll
        for (int i = 0; i < 4; ++i)
          breg[i] = *(const u32x4*)(WoT + (size_t)(b_row + i * 32) * DPROJ + kc2 + b_col);
      }
      asm volatile("s_waitcnt lgkmcnt(0)" ::: "memory");
      __builtin_amdgcn_s_barrier();
    }
  }

  float g[8], be[8];
  #pragma unroll
  for (int ni = 0; ni < 8; ++ni) {
    g[ni] = gamma[ni * 16 + l16];
    be[ni] = beta[ni * 16 + l16];
  }

  float val[8][4];
  #pragma unroll
  for (int r = 0; r < 4; ++r) {
    int m = m0 + w * 16 + quad * 4 + r;
    const float* erow = enc + (size_t)m * HID;
    float s = 0.f, s2 = 0.f;
    #pragma unroll
    for (int ni = 0; ni < 8; ++ni) {
      float v = acc[ni][r] + erow[ni * 16 + l16];
      val[ni][r] = v;
      s += v;
      s2 += v * v;
    }
    #pragma unroll
    for (int off = 1; off < 16; off <<= 1) {
      s  += __shfl_xor(s, off, 64);
      s2 += __shfl_xor(s2, off, 64);
    }
    float mean = s * (1.f / 128.f);
    float var = s2 * (1.f / 128.f) - mean * mean;
    float rstd = rsqrtf(var + 1e-6f);
    float* orow = out + (size_t)m * HID;
    #pragma unroll
    for (int ni = 0; ni < 8; ++ni)
      orow[ni * 16 + l16] = g[ni] * (val[ni][r] - mean) * rstd + be[ni];
  }
}

// ---------------------------------------------------------------------------
// ws layout (elements):
//   WT   : 3*512*128 shorts        WoT : 128*512 shorts
//   Qh   : 4*M*128 shorts          Kh  : 4*M*128 shorts
//   Vt   : 4*64*128*512 shorts     ctx : M*512 shorts
//   encb : M*128 shorts            mbits: 64*512*16 u32
// ---------------------------------------------------------------------------
extern "C" void kernel_launch(void* const* d_in, const int* in_sizes, int n_in,
                              void* d_out, int out_size, void* d_ws, size_t ws_size,
                              hipStream_t stream) {
  const float* enc   = (const float*)d_in[0];
  const int*   mask  = (const int*)d_in[1];
  const float* Wq    = (const float*)d_in[2];
  const float* Wk    = (const float*)d_in[3];
  const float* Wv    = (const float*)d_in[4];
  const float* Wo    = (const float*)d_in[5];
  const float* gamma = (const float*)d_in[6];
  const float* beta  = (const float*)d_in[7];
  float* out = (float*)d_out;

  unsigned short* WT  = (unsigned short*)d_ws;
  unsigned short* WoT = WT + (size_t)3 * DPROJ * HID;
  unsigned short* Qh  = WoT + (size_t)HID * DPROJ;
  unsigned short* Kh  = Qh + (size_t)NHEAD * MTOT * HID;
  unsigned short* Vt  = Kh + (size_t)NHEAD * MTOT * HID;
  unsigned short* ctx = Vt + (size_t)NHEAD * MTOT * HID;
  unsigned short* encb = ctx + (size_t)MTOT * DPROJ;
  unsigned int* mbits = (unsigned int*)(encb + (size_t)MTOT * HID);

  prep_kernel<<<4096, 256, 0, stream>>>(Wq, Wk, Wv, Wo, enc, mask, WT, WoT, encb, mbits);
  qkv_kernel<<<1024, 256, 0, stream>>>(encb, WT, Qh, Kh, Vt);
  attn_kernel<<<1024, 256, 0, stream>>>(Qh, Kh, Vt, mbits, ctx);
  oproj_ln_kernel<<<MTOT / 64, 256, 0, stream>>>(ctx, WoT, enc, gamma, beta, out);
}

// Round 12
// 222.009 us; speedup vs baseline: 1.2212x; 1.0044x over previous
//
#include <hip/hip_runtime.h>
#include <stdint.h>

#define BATCH 64
#define SLEN 512
#define HID 128
#define NHEAD 4
#define DPROJ 512            // HID * NHEAD
#define MTOT (BATCH * SLEN)  // 32768
#define SCALE 0.08838834764831845f
#define LOG2E 1.4426950408889634f

using short8 = __attribute__((ext_vector_type(8))) short;
using f32x4  = __attribute__((ext_vector_type(4))) float;
using u32x4  = __attribute__((ext_vector_type(4))) unsigned int;
using u32x2  = __attribute__((ext_vector_type(2))) unsigned int;
using us4    = __attribute__((ext_vector_type(4))) unsigned short;

__device__ __forceinline__ unsigned short f2bf(float f) {
  unsigned int u = __float_as_uint(f);
  u += 0x7fffu + ((u >> 16) & 1u);   // round-to-nearest-even
  return (unsigned short)(u >> 16);
}

// ---------------------------------------------------------------------------
// Kernel 0: prep — R19 (frozen). Weights + enc cast + vectorized mask pack.
// ---------------------------------------------------------------------------
__global__ __launch_bounds__(256) void prep_kernel(
    const float* __restrict__ Wq,
    const float* __restrict__ Wk,
    const float* __restrict__ Wv,
    const float* __restrict__ Wo,
    const float* __restrict__ enc,
    const int* __restrict__ mask,
    unsigned short* __restrict__ WT,
    unsigned short* __restrict__ WoT,
    unsigned short* __restrict__ encb,
    unsigned int* __restrict__ mbits)
{
  if (blockIdx.x < 1024) {
    int idx = blockIdx.x * 256 + threadIdx.x;
    int z = idx >> 16;
    int i = idx & 65535;
    if (z < 3) {
      const float* W = (z == 0) ? Wq : (z == 1) ? Wk : Wv;
      float scale = (z == 0) ? (SCALE * LOG2E) : 1.0f;  // exp2 form
      int k = i >> 9;
      int n = i & 511;
      WT[(size_t)z * 65536 + (size_t)n * 128 + k] = f2bf(W[i] * scale);
    } else {
      int k = i >> 7;
      int n = i & 127;
      WoT[(size_t)n * 512 + k] = f2bf(Wo[i]);
    }
  } else if (blockIdx.x < 3072) {
    size_t tid = (size_t)(blockIdx.x - 1024) * 256 + threadIdx.x;  // 0..524287
    const float* s = enc + tid * 8;
    f32x4 a0 = *(const f32x4*)(s);
    f32x4 a1 = *(const f32x4*)(s + 4);
    short8 v;
    #pragma unroll
    for (int j = 0; j < 4; ++j) v[j] = (short)f2bf(a0[j]);
    #pragma unroll
    for (int j = 0; j < 4; ++j) v[4 + j] = (short)f2bf(a1[j]);
    *(short8*)(encb + tid * 8) = v;
  } else {
    // mask -> bitmask: 1024 blocks x 4 waves x 16 tiles of 256 ints.
    const int l = threadIdx.x & 63;
    const int wv = threadIdx.x >> 6;
    const int m = blockIdx.x - 3072;
    #pragma unroll 4
    for (int it = 0; it < 16; ++it) {
      size_t tile = (size_t)m * 64 + (size_t)wv * 16 + it;
      u32x4 v = *(const u32x4*)(mask + tile * 256 + l * 4);
      unsigned nib = (v[0] ? 1u : 0u) | (v[1] ? 2u : 0u) |
                     (v[2] ? 4u : 0u) | (v[3] ? 8u : 0u);
      unsigned a  = nib | ((unsigned)__shfl_xor((int)nib, 1, 64) << 4);
      unsigned b2 = a   | ((unsigned)__shfl_xor((int)a,   2, 64) << 8);
      unsigned c  = b2  | ((unsigned)__shfl_xor((int)b2,  4, 64) << 16);
      if ((l & 7) == 0) mbits[tile * 8 + (l >> 3)] = c;
    }
  }
}

// ---------------------------------------------------------------------------
// Kernel 1: QKV projection — R21 (frozen; R14 + XCD-aware decode).
// ---------------------------------------------------------------------------
__global__ __launch_bounds__(256) void qkv_kernel(
    const unsigned short* __restrict__ encb,  // (M,128) bf16
    const unsigned short* __restrict__ WT,    // (3,512,128) bf16 n-major
    unsigned short* __restrict__ Qh,
    unsigned short* __restrict__ Kh,
    unsigned short* __restrict__ Vt)
{
  const int lin = blockIdx.x;            // 0..1023
  const int nt = (lin >> 3) & 3;         // head
  const int mt = (lin & 7) + 8 * (lin >> 5);   // 0..255
  const int t = threadIdx.x;
  const int lane = t & 63;
  const int w = t >> 6;
  const int quad = lane >> 4;
  const int l16 = lane & 15;

  __shared__ __align__(16) unsigned short Ald[128 * 136];     // 34816 B
  __shared__ __align__(16) unsigned short Bld[2][128 * 72];   // 36864 B

  const int m0 = mt * 128, n0 = nt * 128;
  const int wm = (w >> 1) * 64, wn = (w & 1) * 64;

  const int b_row = t >> 3, b_col = (t & 7) << 3;  // B-stage: +32 rows per i

  // prologue: A -> regs -> Ald; B(s=0) -> regs -> Bld[0]; B(s=1) -> regs
  {
    u32x4 areg[8];
    #pragma unroll
    for (int i = 0; i < 8; ++i) {
      int idx = i * 256 + t;
      areg[i] = *(const u32x4*)(encb + (size_t)(m0 + (idx >> 4)) * HID + ((idx & 15) << 3));
    }
    u32x4 breg0[4];
    #pragma unroll
    for (int i = 0; i < 4; ++i)
      breg0[i] = *(const u32x4*)(WT + (size_t)(n0 + b_row + i * 32) * HID + b_col);
    #pragma unroll
    for (int i = 0; i < 8; ++i) {
      int idx = i * 256 + t;
      *(u32x4*)(Ald + (idx >> 4) * 136 + ((idx & 15) << 3)) = areg[i];
    }
    #pragma unroll
    for (int i = 0; i < 4; ++i)
      *(u32x4*)(Bld[0] + (b_row + i * 32) * 72 + b_col) = breg0[i];
  }
  u32x4 breg[4];
  #pragma unroll
  for (int i = 0; i < 4; ++i)   // s=1: z=0, kc=1
    breg[i] = *(const u32x4*)(WT + (size_t)(n0 + b_row + i * 32) * HID + 64 + b_col);
  asm volatile("s_waitcnt lgkmcnt(0)" ::: "memory");
  __builtin_amdgcn_s_barrier();

  f32x4 acc[4][4];
  #pragma unroll
  for (int s = 0; s < 6; ++s) {
    const int z = s >> 1, kc = s & 1, p = s & 1;
    if (kc == 0) {
      #pragma unroll
      for (int mi = 0; mi < 4; ++mi)
        #pragma unroll
        for (int ni = 0; ni < 4; ++ni)
          acc[mi][ni] = f32x4{0.f, 0.f, 0.f, 0.f};
    }

    const unsigned short* Br = Bld[p];
    #pragma unroll
    for (int kk = 0; kk < 2; ++kk) {
      short8 a[4], bb[4];
      #pragma unroll
      for (int mi = 0; mi < 4; ++mi)
        a[mi] = *(const short8*)(Ald + (wm + mi * 16 + l16) * 136 + kc * 64 + kk * 32 + quad * 8);
      #pragma unroll
      for (int ni = 0; ni < 4; ++ni)
        bb[ni] = *(const short8*)(Br + (wn + ni * 16 + l16) * 72 + kk * 32 + quad * 8);
      if (z < 2) {
        #pragma unroll
        for (int mi = 0; mi < 4; ++mi)
          #pragma unroll
          for (int ni = 0; ni < 4; ++ni)
            acc[mi][ni] = __builtin_amdgcn_mfma_f32_16x16x32_bf16(bb[ni], a[mi], acc[mi][ni], 0, 0, 0);
      } else {
        #pragma unroll
        for (int mi = 0; mi < 4; ++mi)
          #pragma unroll
          for (int ni = 0; ni < 4; ++ni)
            acc[mi][ni] = __builtin_amdgcn_mfma_f32_16x16x32_bf16(a[mi], bb[ni], acc[mi][ni], 0, 0, 0);
      }
    }

    if (s < 5) {
      // write prefetched B(s+1) into the idle buffer; issue loads for s+2
      unsigned short* Bw2 = Bld[p ^ 1];
      #pragma unroll
      for (int i = 0; i < 4; ++i)
        *(u32x4*)(Bw2 + (b_row + i * 32) * 72 + b_col) = breg[i];
      if (s < 4) {
        const int s2 = s + 2;
        const unsigned short* Wz = WT + (size_t)(s2 >> 1) * DPROJ * HID;
        #pragma unroll
        for (int i = 0; i < 4; ++i)
          breg[i] = *(const u32x4*)(Wz + (size_t)(n0 + b_row + i * 32) * HID + (s2 & 1) * 64 + b_col);
      }
      asm volatile("s_waitcnt lgkmcnt(0)" ::: "memory");
      __builtin_amdgcn_s_barrier();
    }

    if (kc == 1) {
      if (z < 2) {
        // D[n][m]: col(l16)=m-within-16, row(quad*4+r)=d-within-16
        unsigned short* outz = ((z == 0) ? Qh : Kh) + (size_t)nt * MTOT * HID;
        #pragma unroll
        for (int mi = 0; mi < 4; ++mi)
          #pragma unroll
          for (int ni = 0; ni < 4; ++ni) {
            int m = m0 + wm + mi * 16 + l16;
            int dbase = wn + ni * 16 + quad * 4;
            us4 pk;
            #pragma unroll
            for (int r = 0; r < 4; ++r) pk[r] = f2bf(acc[mi][ni][r]);
            *(us4*)(outz + (size_t)m * HID + dbase) = pk;
          }
      } else {
        // D[m][n]: reg axis = s (4 consecutive) -> Vt[(nt*B+b)*128 + d][s]
        #pragma unroll
        for (int mi = 0; mi < 4; ++mi)
          #pragma unroll
          for (int ni = 0; ni < 4; ++ni) {
            int row0 = m0 + wm + mi * 16 + quad * 4;
            int b = row0 >> 9, sres = row0 & 511;
            int d = wn + ni * 16 + l16;
            us4 pk;
            #pragma unroll
            for (int r = 0; r < 4; ++r) pk[r] = f2bf(acc[mi][ni][r]);
            *(us4*)(Vt + ((size_t)(nt * BATCH + b) * HID + d) * SLEN + sres) = pk;
          }
      }
    }
  }
}

// ---------------------------------------------------------------------------
// Kernel 2: flash attention — R20 (frozen; 55.0us, VGPR 116).
// ---------------------------------------------------------------------------
__global__ __launch_bounds__(256, 2) void attn_kernel(
    const unsigned short* __restrict__ Qh,   // (NH, M, 128)
    const unsigned short* __restrict__ Kh,   // (NH, M, 128)
    const unsigned short* __restrict__ Vt,   // (NH, B, 128, S)
    const unsigned int* __restrict__ mbits,  // (B, S, 16)
    unsigned short* __restrict__ ctx)        // (M, 512)
{
  const int lin = blockIdx.x;              // 0..1023
  const int work = (lin & 7) * 128 + (lin >> 3);
  const int qt = work & 3;
  const int h  = (work >> 2) & 3;
  const int b  = work >> 4;

  const int t = threadIdx.x;               // 0..255
  const int lane = t & 63;
  const int w = t >> 6;                    // 0..3
  const int quad = lane >> 4;
  const int l16 = lane & 15;

  __shared__ __align__(16) unsigned short Kld[2][64 * 136];   // 34816 B
  __shared__ __align__(16) unsigned short Vtld[2][128 * 72];  // 36864 B

  const int q0 = qt * 128;
  const size_t rowbase = (size_t)b * SLEN;
  const unsigned short* kbase0 = Kh + ((size_t)h * MTOT + rowbase) * HID;
  const unsigned short* vbase  = Vt + (size_t)(h * BATCH + b) * HID * SLEN;
  const unsigned int* mrow = mbits + (size_t)b * SLEN * 16;

  const int k_key = t >> 4, k_col = (t & 15) << 3;   // +16 keys per i (4 i)
  const int v_d   = t >> 3, v_cc  = (t & 7) << 3;    // +32 d per i (4 i)

  // Q for this wave's 32 rows, held in registers (32 VGPR)
  short8 qa[2][4];
  #pragma unroll
  for (int mi = 0; mi < 2; ++mi) {
    const unsigned short* qbase =
        Qh + ((size_t)h * MTOT + rowbase + q0 + w * 32 + mi * 16 + l16) * HID + quad * 8;
    #pragma unroll
    for (int kk = 0; kk < 4; ++kk)
      qa[mi][kk] = *(const short8*)(qbase + kk * 32);
  }

  short8 ones;
  #pragma unroll
  for (int j = 0; j < 8; ++j) ones[j] = (short)0x3F80;  // bf16 1.0

  f32x4 oc[2][8], oc9[2];
  #pragma unroll
  for (int mi = 0; mi < 2; ++mi) {
    #pragma unroll
    for (int nd = 0; nd < 8; ++nd) oc[mi][nd] = f32x4{0.f, 0.f, 0.f, 0.f};
    oc9[mi] = f32x4{0.f, 0.f, 0.f, 0.f};
  }

  // per-lane q-row mask bases (one per mi)
  const unsigned int* mq0 = mrow + (size_t)(q0 + w * 32 + l16) * 16;
  const unsigned int* mq1 = mq0 + 256;   // +16 rows x 16 words

  // prologue: chunk0 -> regs -> buf0; chunk1 -> regs; barrier
  u32x4 kreg[4], vreg[4];
  #pragma unroll
  for (int i = 0; i < 4; ++i) {
    kreg[i] = *(const u32x4*)(kbase0 + (size_t)(k_key + i * 16) * HID + k_col);
    vreg[i] = *(const u32x4*)(vbase + (size_t)(v_d + i * 32) * SLEN + v_cc);
  }
  #pragma unroll
  for (int i = 0; i < 4; ++i) {
    *(u32x4*)(Kld[0] + (k_key + i * 16) * 136 + k_col) = kreg[i];
    *(u32x4*)(Vtld[0] + (v_d + i * 32) * 72 + v_cc) = vreg[i];
  }
  #pragma unroll
  for (int i = 0; i < 4; ++i) {
    kreg[i] = *(const u32x4*)(kbase0 + (size_t)(64 + k_key + i * 16) * HID + k_col);
    vreg[i] = *(const u32x4*)(vbase + (size_t)(v_d + i * 32) * SLEN + 64 + v_cc);
  }
  asm volatile("s_waitcnt lgkmcnt(0)" ::: "memory");
  __builtin_amdgcn_s_barrier();

  for (int c0 = 0; c0 < SLEN; c0 += 64) {
    const int p = (c0 >> 6) & 1;
    const unsigned short* Kr = Kld[p];
    const unsigned short* Vr = Vtld[p];

    // stage chunk c+1 into the idle buffer; issue K loads for c+2
    if (c0 + 64 < SLEN) {
      unsigned short* Kw = Kld[p ^ 1];
      unsigned short* Vw = Vtld[p ^ 1];
      #pragma unroll
      for (int i = 0; i < 4; ++i) {
        *(u32x4*)(Kw + (k_key + i * 16) * 136 + k_col) = kreg[i];
        *(u32x4*)(Vw + (v_d + i * 32) * 72 + v_cc) = vreg[i];
      }
      if (c0 + 128 < SLEN) {
        #pragma unroll
        for (int i = 0; i < 4; ++i)
          kreg[i] = *(const u32x4*)(kbase0 + (size_t)(c0 + 128 + k_key + i * 16) * HID + k_col);
      }
    }

    u32x2 mw0 = *(const u32x2*)(mq0 + (c0 >> 5));
    u32x2 mw1 = *(const u32x2*)(mq1 + (c0 >> 5));

    // S^T via swapped operands; each bb read feeds both mi
    f32x4 sc[2][4];
    #pragma unroll
    for (int mi = 0; mi < 2; ++mi)
      #pragma unroll
      for (int ni = 0; ni < 4; ++ni) sc[mi][ni] = f32x4{0.f, 0.f, 0.f, 0.f};
    __builtin_amdgcn_s_setprio(1);
    #pragma unroll
    for (int kk = 0; kk < 4; ++kk) {
      #pragma unroll
      for (int ni = 0; ni < 4; ++ni) {
        short8 bb = *(const short8*)(Kr + (ni * 16 + l16) * 136 + kk * 32 + quad * 8);
        sc[0][ni] = __builtin_amdgcn_mfma_f32_16x16x32_bf16(bb, qa[0][kk], sc[0][ni], 0, 0, 0);
        sc[1][ni] = __builtin_amdgcn_mfma_f32_16x16x32_bf16(bb, qa[1][kk], sc[1][ni], 0, 0, 0);
      }
    }
    __builtin_amdgcn_s_setprio(0);

    // V prefetch for c+2: latency covered by softmax + PV
    if (c0 + 128 < SLEN) {
      #pragma unroll
      for (int i = 0; i < 4; ++i)
        vreg[i] = *(const u32x4*)(vbase + (size_t)(v_d + i * 32) * SLEN + c0 + 128 + v_cc);
    }

    // softmax per row-group -> PV A-frags in registers (R12 path, per mi)
    short8 aF[2][2];
    #pragma unroll
    for (int mi = 0; mi < 2; ++mi) {
      u32x2 mw = (mi == 0) ? mw0 : mw1;
      unsigned int pk[4][2];
      #pragma unroll
      for (int ni = 0; ni < 4; ++ni) {
        unsigned wsel = (ni < 2) ? mw[0] : mw[1];
        float pp[4];
        #pragma unroll
        for (int r = 0; r < 4; ++r) {
          int bit = (ni & 1) * 16 + quad * 4 + r;
          float e = __builtin_amdgcn_exp2f(sc[mi][ni][r]);   // raw v_exp_f32
          pp[r] = ((wsel >> bit) & 1u) ? e : 0.f;
        }
        asm("v_cvt_pk_bf16_f32 %0, %1, %2" : "=v"(pk[ni][0]) : "v"(pp[0]), "v"(pp[1]));
        asm("v_cvt_pk_bf16_f32 %0, %1, %2" : "=v"(pk[ni][1]) : "v"(pp[2]), "v"(pp[3]));
      }
      #pragma unroll
      for (int kb = 0; kb < 2; ++kb) {
        unsigned int c0w = pk[kb * 2][0], c2w = pk[kb * 2 + 1][0];
        asm("v_permlane32_swap_b32 %0, %1" : "+v"(c0w), "+v"(c2w));
        asm("v_permlane16_swap_b32 %0, %1" : "+v"(c0w), "+v"(c2w));
        unsigned int c1w = pk[kb * 2][1], c3w = pk[kb * 2 + 1][1];
        asm("v_permlane32_swap_b32 %0, %1" : "+v"(c1w), "+v"(c3w));
        asm("v_permlane16_swap_b32 %0, %1" : "+v"(c1w), "+v"(c3w));
        aF[mi][kb] = __builtin_bit_cast(short8, u32x4{c0w, c1w, c2w, c3w});
      }
    }

    // O += P @ V ; rowsum += P @ 1 ; each bv read feeds both mi
    __builtin_amdgcn_s_setprio(1);
    #pragma unroll
    for (int kb = 0; kb < 2; ++kb) {
      #pragma unroll
      for (int nd = 0; nd < 8; ++nd) {
        short8 bv = *(const short8*)(Vr + (nd * 16 + l16) * 72 + kb * 32 + quad * 8);
        oc[0][nd] = __builtin_amdgcn_mfma_f32_16x16x32_bf16(aF[0][kb], bv, oc[0][nd], 0, 0, 0);
        oc[1][nd] = __builtin_amdgcn_mfma_f32_16x16x32_bf16(aF[1][kb], bv, oc[1][nd], 0, 0, 0);
      }
      oc9[0] = __builtin_amdgcn_mfma_f32_16x16x32_bf16(aF[0][kb], ones, oc9[0], 0, 0, 0);
      oc9[1] = __builtin_amdgcn_mfma_f32_16x16x32_bf16(aF[1][kb], ones, oc9[1], 0, 0, 0);
    }
    __builtin_amdgcn_s_setprio(0);

    // one barrier per chunk; vmcnt NOT drained (c+2 loads stay in flight)
    if (c0 + 64 < SLEN) {
      asm volatile("s_waitcnt lgkmcnt(0)" ::: "memory");
      __builtin_amdgcn_s_barrier();
    }
  }

  // epilogue: rcp once per row, multiply
  #pragma unroll
  for (int mi = 0; mi < 2; ++mi) {
    float rcp[4];
    #pragma unroll
    for (int r = 0; r < 4; ++r) rcp[r] = __builtin_amdgcn_rcpf(oc9[mi][r]);
    #pragma unroll
    for (int nd = 0; nd < 8; ++nd)
      #pragma unroll
      for (int r = 0; r < 4; ++r) {
        float val = oc[mi][nd][r] * rcp[r];
        int row = q0 + w * 32 + mi * 16 + quad * 4 + r;
        int col = h * HID + nd * 16 + l16;
        ctx[(rowbase + row) * DPROJ + col] = f2bf(val);
      }
  }
}

// ---------------------------------------------------------------------------
// Kernel 3: output projection + residual + LayerNorm — R22.
// R14 oproj (512 blocks x 64 rows): B (WoT) staged twice per 128 rows,
// 16 barriers / 128 rows, 6 staging vec8/thread/stage. R22: 256 blocks x
// 512 threads x 128 rows (8 waves x 16 rows; inner loop byte-identical per
// wave): B staged ONCE per 128 rows, barriers per row halved, staging 4
// vec8/thread/stage. TLP unchanged (1 blk/CU x 8 waves = 2 waves/SIMD ==
// old 2 blk x 4 waves). Same single-lgkm-barrier pipeline + hazard rules.
// LDS 73,728 B. launch_bounds(512,2) -> 256 VGPR cap (liveness ~100).
// ---------------------------------------------------------------------------
__global__ __launch_bounds__(512, 2) void oproj_ln_kernel(
    const unsigned short* __restrict__ ctx,   // (M,512) bf16
    const unsigned short* __restrict__ WoT,   // (128,512) bf16 n-major
    const float* __restrict__ enc,            // (M,128) fp32
    const float* __restrict__ gamma,
    const float* __restrict__ beta,
    float* __restrict__ out)                  // (M,128) fp32
{
  const int m0 = blockIdx.x * 128;
  const int t = threadIdx.x;       // 0..511
  const int lane = t & 63;
  const int w = t >> 6;            // 0..7
  const int quad = lane >> 4;
  const int l16 = lane & 15;

  __shared__ __align__(16) unsigned short Actx[2][128 * 72];  // 36864 B
  __shared__ __align__(16) unsigned short Bw[2][128 * 72];    // 36864 B

  // staging decode: 1024 vec8 per (A or B) stage, 2 per thread
  const int s_row = t >> 3;            // 0..63; +64 at i=1
  const int s_col = (t & 7) << 3;

  f32x4 acc[8];
  #pragma unroll
  for (int ni = 0; ni < 8; ++ni) acc[ni] = f32x4{0.f, 0.f, 0.f, 0.f};

  // prologue: (kc=0) -> regs -> buf0; (kc=1) -> regs; barrier
  u32x4 areg[2], breg[2];
  #pragma unroll
  for (int i = 0; i < 2; ++i) {
    areg[i] = *(const u32x4*)(ctx + (size_t)(m0 + s_row + i * 64) * DPROJ + s_col);
    breg[i] = *(const u32x4*)(WoT + (size_t)(s_row + i * 64) * DPROJ + s_col);
  }
  #pragma unroll
  for (int i = 0; i < 2; ++i) {
    *(u32x4*)(Actx[0] + (s_row + i * 64) * 72 + s_col) = areg[i];
    *(u32x4*)(Bw[0] + (s_row + i * 64) * 72 + s_col) = breg[i];
  }
  #pragma unroll
  for (int i = 0; i < 2; ++i) {
    areg[i] = *(const u32x4*)(ctx + (size_t)(m0 + s_row + i * 64) * DPROJ + 64 + s_col);
    breg[i] = *(const u32x4*)(WoT + (size_t)(s_row + i * 64) * DPROJ + 64 + s_col);
  }
  asm volatile("s_waitcnt lgkmcnt(0)" ::: "memory");
  __builtin_amdgcn_s_barrier();

  #pragma unroll
  for (int it = 0; it < 8; ++it) {
    const int p = it & 1;
    const unsigned short* Ar = Actx[p];
    const unsigned short* Br = Bw[p];
    #pragma unroll
    for (int kk = 0; kk < 2; ++kk) {
      short8 a = *(const short8*)(Ar + (w * 16 + l16) * 72 + kk * 32 + quad * 8);
      #pragma unroll
      for (int ni = 0; ni < 8; ++ni) {
        short8 bb = *(const short8*)(Br + (ni * 16 + l16) * 72 + kk * 32 + quad * 8);
        acc[ni] = __builtin_amdgcn_mfma_f32_16x16x32_bf16(a, bb, acc[ni], 0, 0, 0);
      }
    }
    if (it < 7) {
      unsigned short* Aw2 = Actx[p ^ 1];
      unsigned short* Bw2 = Bw[p ^ 1];
      #pragma unroll
      for (int i = 0; i < 2; ++i) {
        *(u32x4*)(Aw2 + (s_row + i * 64) * 72 + s_col) = areg[i];
        *(u32x4*)(Bw2 + (s_row + i * 64) * 72 + s_col) = breg[i];
      }
      if (it < 6) {
        const int kc2 = (it + 2) * 64;
        #pragma unroll
        for (int i = 0; i < 2; ++i) {
          areg[i] = *(const u32x4*)(ctx + (size_t)(m0 + s_row + i * 64) * DPROJ + kc2 + s_col);
          breg[i] = *(const u32x4*)(WoT + (size_t)(s_row + i * 64) * DPROJ + kc2 + s_col);
        }
      }
      asm volatile("s_waitcnt lgkmcnt(0)" ::: "memory");
      __builtin_amdgcn_s_barrier();
    }
  }

  float g[8], be[8];
  #pragma unroll
  for (int ni = 0; ni < 8; ++ni) {
    g[ni] = gamma[ni * 16 + l16];
    be[ni] = beta[ni * 16 + l16];
  }

  float val[8][4];
  #pragma unroll
  for (int r = 0; r < 4; ++r) {
    int m = m0 + w * 16 + quad * 4 + r;
    const float* erow = enc + (size_t)m * HID;
    float s = 0.f, s2 = 0.f;
    #pragma unroll
    for (int ni = 0; ni < 8; ++ni) {
      float v = acc[ni][r] + erow[ni * 16 + l16];
      val[ni][r] = v;
      s += v;
      s2 += v * v;
    }
    #pragma unroll
    for (int off = 1; off < 16; off <<= 1) {
      s  += __shfl_xor(s, off, 64);
      s2 += __shfl_xor(s2, off, 64);
    }
    float mean = s * (1.f / 128.f);
    float var = s2 * (1.f / 128.f) - mean * mean;
    float rstd = rsqrtf(var + 1e-6f);
    float* orow = out + (size_t)m * HID;
    #pragma unroll
    for (int ni = 0; ni < 8; ++ni)
      orow[ni * 16 + l16] = g[ni] * (val[ni][r] - mean) * rstd + be[ni];
  }
}

// ---------------------------------------------------------------------------
// ws layout (elements):
//   WT   : 3*512*128 shorts        WoT : 128*512 shorts
//   Qh   : 4*M*128 shorts          Kh  : 4*M*128 shorts
//   Vt   : 4*64*128*512 shorts     ctx : M*512 shorts
//   encb : M*128 shorts            mbits: 64*512*16 u32
// ---------------------------------------------------------------------------
extern "C" void kernel_launch(void* const* d_in, const int* in_sizes, int n_in,
                              void* d_out, int out_size, void* d_ws, size_t ws_size,
                              hipStream_t stream) {
  const float* enc   = (const float*)d_in[0];
  const int*   mask  = (const int*)d_in[1];
  const float* Wq    = (const float*)d_in[2];
  const float* Wk    = (const float*)d_in[3];
  const float* Wv    = (const float*)d_in[4];
  const float* Wo    = (const float*)d_in[5];
  const float* gamma = (const float*)d_in[6];
  const float* beta  = (const float*)d_in[7];
  float* out = (float*)d_out;

  unsigned short* WT  = (unsigned short*)d_ws;
  unsigned short* WoT = WT + (size_t)3 * DPROJ * HID;
  unsigned short* Qh  = WoT + (size_t)HID * DPROJ;
  unsigned short* Kh  = Qh + (size_t)NHEAD * MTOT * HID;
  unsigned short* Vt  = Kh + (size_t)NHEAD * MTOT * HID;
  unsigned short* ctx = Vt + (size_t)NHEAD * MTOT * HID;
  unsigned short* encb = ctx + (size_t)MTOT * DPROJ;
  unsigned int* mbits = (unsigned int*)(encb + (size_t)MTOT * HID);

  prep_kernel<<<4096, 256, 0, stream>>>(Wq, Wk, Wv, Wo, enc, mask, WT, WoT, encb, mbits);
  qkv_kernel<<<1024, 256, 0, stream>>>(encb, WT, Qh, Kh, Vt);
  attn_kernel<<<1024, 256, 0, stream>>>(Qh, Kh, Vt, mbits, ctx);
  oproj_ln_kernel<<<MTOT / 128, 512, 0, stream>>>(ctx, WoT, enc, gamma, beta, out);
}